// Round 6
// baseline (1220.412 us; speedup 1.0000x reference)
//
#include <hip/hip_runtime.h>
#include <hip/hip_bf16.h>
#include <math.h>

#define B_ 16
#define S_ 512
#define D_ 512
#define H_ 8
#define L_ 6
#define DPH_ 64
#define DFF_ 2048
#define VOCAB_ 1024
#define NPC_ 4096
#define NS_ 4096
#define BS_ (B_ * S_)   // 8192 rows
#define LOG2E 1.4426950408889634f

typedef __attribute__((ext_vector_type(8))) short bf16x8;
typedef __attribute__((ext_vector_type(4))) float f32x4;

__device__ __forceinline__ ushort f2bf(float f) {
    __hip_bfloat16 h = __float2bfloat16(f);
    return __builtin_bit_cast(ushort, h);
}
__device__ __forceinline__ float bf2f(ushort u) {
    unsigned int v = ((unsigned int)u) << 16;
    return __builtin_bit_cast(float, v);
}

// ---------------------------------------------------------------------------
// Embedding
// ---------------------------------------------------------------------------
__global__ __launch_bounds__(256) void embed_kernel(
    const int* __restrict__ raw_x, const int* __restrict__ sdeg,
    const float* __restrict__ vemb, const float* __restrict__ demb,
    float* __restrict__ x)
{
    size_t idx = (size_t)blockIdx.x * 256 + threadIdx.x;
    int d = (int)(idx & (D_ - 1));
    size_t bs = idx >> 9;
    int s = (int)(bs & (S_ - 1));
    int tok = raw_x[bs];
    int dg  = sdeg[bs];
    float e = expf(-(float)(d & ~1) * (9.210340371976184f / (float)D_));
    float ang = (float)s * e;
    float pe = (d & 1) ? cosf(ang) : sinf(ang);
    x[idx] = vemb[(size_t)tok * D_ + d] + pe + demb[(size_t)dg * D_ + d];
}

__global__ void relnow_kernel(const int* __restrict__ pcn, const int* __restrict__ sbn,
                              const float* __restrict__ arel, float* __restrict__ x)
{
    int b = blockIdx.x;
    int t = threadIdx.x;   // 512 threads
    int b1 = pcn[b * 2 + 0], p1 = pcn[b * 2 + 1];
    x[((size_t)(b1 * S_ + p1)) * D_ + t] += arel[t];
    int b2 = sbn[b * 2 + 0], p2 = sbn[b * 2 + 1];
    x[((size_t)(b2 * S_ + p2)) * D_ + t] += arel[D_ + t];
}

__global__ void bias_scatter_kernel(const int* __restrict__ pc, const int* __restrict__ sb,
                                    const float* __restrict__ renc, float* __restrict__ bias)
{
    int t = blockIdx.x * 256 + threadIdx.x;
    float r0 = renc[0], r1 = renc[1], r2 = renc[2];
    if (t < NPC_) {
        int b = pc[t * 3 + 0], i = pc[t * 3 + 1], j = pc[t * 3 + 2];
        atomicAdd(&bias[((size_t)b * S_ + i) * S_ + j], r0);
        atomicAdd(&bias[((size_t)b * S_ + j) * S_ + i], r1);
    } else if (t < NPC_ + NS_) {
        int u = t - NPC_;
        int b = sb[u * 3 + 0], i = sb[u * 3 + 1], j = sb[u * 3 + 2];
        atomicAdd(&bias[((size_t)b * S_ + i) * S_ + j], r2);
        atomicAdd(&bias[((size_t)b * S_ + j) * S_ + i], r2);
    }
}

// bias fp32 -> bf16 scaled by log2(e)
__global__ __launch_bounds__(256) void bias_cast_kernel(const float* __restrict__ src,
                                                        ushort* __restrict__ dst)
{
    int i = blockIdx.x * 256 + threadIdx.x;   // < B*S*S/4
    float4 v = ((const float4*)src)[i];
    ushort4 o;
    o.x = f2bf(v.x * LOG2E); o.y = f2bf(v.y * LOG2E);
    o.z = f2bf(v.z * LOG2E); o.w = f2bf(v.w * LOG2E);
    ((ushort4*)dst)[i] = o;
}

// ---------------------------------------------------------------------------
// Weight prep
// ---------------------------------------------------------------------------
__global__ __launch_bounds__(256) void cast4_kernel(const float* __restrict__ src,
                                                    ushort* __restrict__ dst, int n4)
{
    int i = blockIdx.x * 256 + threadIdx.x;
    if (i >= n4) return;
    float4 v = ((const float4*)src)[i];
    ushort4 o;
    o.x = f2bf(v.x); o.y = f2bf(v.y); o.z = f2bf(v.z); o.w = f2bf(v.w);
    ((ushort4*)dst)[i] = o;
}

__global__ __launch_bounds__(256) void pack_qkv_kernel(
    const float* __restrict__ Wq, const float* __restrict__ Wk, const float* __restrict__ Wv,
    ushort* __restrict__ dst)
{
    int idx = blockIdx.x * 256 + threadIdx.x;   // < L*1536*512
    int c = idx & 511;
    int rl = idx >> 9;
    int r = rl % 1536, l = rl / 1536;
    float v;
    if (r < 512)       v = Wq[((size_t)l * 512 + r) * 512 + c];
    else if (r < 1024) v = Wk[((size_t)l * 512 + (r - 512)) * 512 + c];
    else               v = Wv[((size_t)l * 512 + (r - 1024)) * 512 + c];
    dst[idx] = f2bf(v);
}

__global__ void pack_bqkv_kernel(const float* __restrict__ bq, const float* __restrict__ bk,
                                 const float* __restrict__ bv, float* __restrict__ dst)
{
    int idx = blockIdx.x * 256 + threadIdx.x;
    if (idx >= L_ * 1536) return;
    int r = idx % 1536, l = idx / 1536;
    float v;
    if (r < 512)       v = bq[l * 512 + r];
    else if (r < 1024) v = bk[l * 512 + r - 512];
    else               v = bv[l * 512 + r - 1024];
    dst[idx] = v;
}

// ---------------------------------------------------------------------------
// bf16 MFMA NT GEMM, 128x128 tile, BK=64 via two proven 32-k LDS buffers.
// C[n,m] = sum_k A[n,k]*W[m,k] + bias[m].  mode 1: bf16+relu. mode 2: bf16.
// ---------------------------------------------------------------------------
#define GL2LDS(g, l) __builtin_amdgcn_global_load_lds( \
    (const __attribute__((address_space(1))) void*)(g), \
    (__attribute__((address_space(3))) void*)(l), 16, 0, 0)

__global__ __launch_bounds__(256) void gemm_bf16(
    const ushort* __restrict__ A, const ushort* __restrict__ W,
    const float* __restrict__ bias, ushort* __restrict__ Cb,
    int K, int M, int mode)
{
    __shared__ ushort As0[128 * 32];
    __shared__ ushort As1[128 * 32];
    __shared__ ushort Bs0[128 * 32];
    __shared__ ushort Bs1[128 * 32];

    const int t  = threadIdx.x;
    const int wv = t >> 6;
    const int ln = t & 63;
    const int wm = wv >> 1, wn = wv & 1;
    const int lq = ln >> 4, lc = ln & 15;
    const int row0 = blockIdx.y * 128;
    const int col0 = blockIdx.x * 128;
    const int lr = ln >> 2;
    const int lk = (ln & 3) * 8;

    f32x4 acc[4][4] = {};

    for (int k0 = 0; k0 < K; k0 += 64) {
        #pragma unroll
        for (int i = 0; i < 2; i++) {
            int r = i * 64 + wv * 16;
            const ushort* ga = A + (size_t)(row0 + r + lr) * K + k0 + lk;
            const ushort* gb = W + (size_t)(col0 + r + lr) * K + k0 + lk;
            GL2LDS(ga,      &As0[r * 32]);
            GL2LDS(gb,      &Bs0[r * 32]);
            GL2LDS(ga + 32, &As1[r * 32]);
            GL2LDS(gb + 32, &Bs1[r * 32]);
        }
        __syncthreads();

        bf16x8 af[4], bf[4];
        #pragma unroll
        for (int mi = 0; mi < 4; mi++)
            af[mi] = *(const bf16x8*)&As0[(wm * 64 + mi * 16 + lc) * 32 + lq * 8];
        #pragma unroll
        for (int ni = 0; ni < 4; ni++)
            bf[ni] = *(const bf16x8*)&Bs0[(wn * 64 + ni * 16 + lc) * 32 + lq * 8];
        #pragma unroll
        for (int mi = 0; mi < 4; mi++)
            #pragma unroll
            for (int ni = 0; ni < 4; ni++)
                acc[mi][ni] = __builtin_amdgcn_mfma_f32_16x16x32_bf16(af[mi], bf[ni], acc[mi][ni], 0, 0, 0);

        #pragma unroll
        for (int mi = 0; mi < 4; mi++)
            af[mi] = *(const bf16x8*)&As1[(wm * 64 + mi * 16 + lc) * 32 + lq * 8];
        #pragma unroll
        for (int ni = 0; ni < 4; ni++)
            bf[ni] = *(const bf16x8*)&Bs1[(wn * 64 + ni * 16 + lc) * 32 + lq * 8];
        #pragma unroll
        for (int mi = 0; mi < 4; mi++)
            #pragma unroll
            for (int ni = 0; ni < 4; ni++)
                acc[mi][ni] = __builtin_amdgcn_mfma_f32_16x16x32_bf16(af[mi], bf[ni], acc[mi][ni], 0, 0, 0);
        __syncthreads();
    }

    #pragma unroll
    for (int mi = 0; mi < 4; mi++) {
        #pragma unroll
        for (int ni = 0; ni < 4; ni++) {
            int gcol = col0 + wn * 64 + ni * 16 + lc;
            float bb = bias[gcol];
            #pragma unroll
            for (int rr = 0; rr < 4; rr++) {
                int grow = row0 + wm * 64 + mi * 16 + lq * 4 + rr;
                float val = acc[mi][ni][rr] + bb;
                if (mode == 1) val = fmaxf(val, 0.f);
                Cb[(size_t)grow * M + gcol] = f2bf(val);
            }
        }
    }
}

// ---------------------------------------------------------------------------
// 128x64-col tile, full-K, fp32 out (no bias — folded into add_ln).
// Grid (M/64, N/128) -> 512 blocks for M=512: occupancy without split-K.
// ---------------------------------------------------------------------------
__global__ __launch_bounds__(256) void gemm64(
    const ushort* __restrict__ A, const ushort* __restrict__ W,
    float* __restrict__ C, int K, int M)
{
    __shared__ ushort As0[128 * 32];
    __shared__ ushort As1[128 * 32];
    __shared__ ushort Bs0[64 * 32];
    __shared__ ushort Bs1[64 * 32];

    const int t  = threadIdx.x;
    const int wv = t >> 6;
    const int ln = t & 63;
    const int wm = wv >> 1, wn = wv & 1;
    const int lq = ln >> 4, lc = ln & 15;
    const int row0 = blockIdx.y * 128;
    const int col0 = blockIdx.x * 64;
    const int lr = ln >> 2;
    const int lk = (ln & 3) * 8;

    f32x4 acc[4][2] = {};

    for (int k0 = 0; k0 < K; k0 += 64) {
        #pragma unroll
        for (int i = 0; i < 2; i++) {
            int r = i * 64 + wv * 16;
            const ushort* ga = A + (size_t)(row0 + r + lr) * K + k0 + lk;
            GL2LDS(ga,      &As0[r * 32]);
            GL2LDS(ga + 32, &As1[r * 32]);
        }
        {
            int rb = wv * 16;
            const ushort* gb = W + (size_t)(col0 + rb + lr) * K + k0 + lk;
            GL2LDS(gb,      &Bs0[rb * 32]);
            GL2LDS(gb + 32, &Bs1[rb * 32]);
        }
        __syncthreads();

        bf16x8 af[4], bf[2];
        #pragma unroll
        for (int mi = 0; mi < 4; mi++)
            af[mi] = *(const bf16x8*)&As0[(wm * 64 + mi * 16 + lc) * 32 + lq * 8];
        #pragma unroll
        for (int ni = 0; ni < 2; ni++)
            bf[ni] = *(const bf16x8*)&Bs0[(wn * 32 + ni * 16 + lc) * 32 + lq * 8];
        #pragma unroll
        for (int mi = 0; mi < 4; mi++)
            #pragma unroll
            for (int ni = 0; ni < 2; ni++)
                acc[mi][ni] = __builtin_amdgcn_mfma_f32_16x16x32_bf16(af[mi], bf[ni], acc[mi][ni], 0, 0, 0);

        #pragma unroll
        for (int mi = 0; mi < 4; mi++)
            af[mi] = *(const bf16x8*)&As1[(wm * 64 + mi * 16 + lc) * 32 + lq * 8];
        #pragma unroll
        for (int ni = 0; ni < 2; ni++)
            bf[ni] = *(const bf16x8*)&Bs1[(wn * 32 + ni * 16 + lc) * 32 + lq * 8];
        #pragma unroll
        for (int mi = 0; mi < 4; mi++)
            #pragma unroll
            for (int ni = 0; ni < 2; ni++)
                acc[mi][ni] = __builtin_amdgcn_mfma_f32_16x16x32_bf16(af[mi], bf[ni], acc[mi][ni], 0, 0, 0);
        __syncthreads();
    }

    #pragma unroll
    for (int mi = 0; mi < 4; mi++)
        #pragma unroll
        for (int ni = 0; ni < 2; ni++) {
            int gcol = col0 + wn * 32 + ni * 16 + lc;
            #pragma unroll
            for (int rr = 0; rr < 4; rr++) {
                int grow = row0 + wm * 64 + mi * 16 + lq * 4 + rr;
                C[(size_t)grow * M + gcol] = acc[mi][ni][rr];
            }
        }
}

// ---------------------------------------------------------------------------
// MFMA flash attention, no-max softmax (unchanged from R5)
// ---------------------------------------------------------------------------
#define PSTR 72

__device__ __forceinline__ int vswz(int d, int j) {
    int g = ((j >> 3) ^ (d & 7) ^ ((d >> 3) & 7)) & 7;
    return d * 64 + g * 8 + (j & 7);
}

__global__ __launch_bounds__(256) void attn_kernel(
    const ushort* __restrict__ qkv, const ushort* __restrict__ biasb,
    ushort* __restrict__ ao)
{
    const int qt = blockIdx.x, h = blockIdx.y, b = blockIdx.z;
    const int t  = threadIdx.x;
    const int wq = t >> 6;
    const int ln = t & 63;
    const int lq = ln >> 4;
    const int lc = ln & 15;
    const int r  = t >> 2;
    const int cg = t & 3;

    __shared__ ushort Qs[64 * PSTR];
    __shared__ ushort Ks[64 * PSTR];
    __shared__ ushort Ps[64 * PSTR];
    __shared__ ushort Vts[64 * 64];

    const int i0 = qt * 64;

    {
        const ushort* qsrc = qkv + (size_t)(b * S_ + i0 + r) * 1536 + h * 64 + cg * 16;
        *(uint4*)&Qs[r * PSTR + cg * 16]     = ((const uint4*)qsrc)[0];
        *(uint4*)&Qs[r * PSTR + cg * 16 + 8] = ((const uint4*)qsrc)[1];
    }
    bf16x8 aq0 = *(const bf16x8*)&Qs[(wq * 16 + lc) * PSTR + lq * 8];
    bf16x8 aq1 = *(const bf16x8*)&Qs[(wq * 16 + lc) * PSTR + 32 + lq * 8];

    f32x4 of[4] = {};
    float l_lane[4] = {};
    const float QSC = 0.125f * LOG2E;

    for (int j0 = 0; j0 < S_; j0 += 64) {
        __syncthreads();
        {
            const ushort* ksrc = qkv + (size_t)(b * S_ + j0 + r) * 1536 + 512 + h * 64 + cg * 16;
            *(uint4*)&Ks[r * PSTR + cg * 16]     = ((const uint4*)ksrc)[0];
            *(uint4*)&Ks[r * PSTR + cg * 16 + 8] = ((const uint4*)ksrc)[1];
            const ushort* vsrc = ksrc + 512;
            ushort vv[16];
            *(uint4*)&vv[0] = ((const uint4*)vsrc)[0];
            *(uint4*)&vv[8] = ((const uint4*)vsrc)[1];
            #pragma unroll
            for (int dd = 0; dd < 16; dd++)
                Vts[vswz(cg * 16 + dd, r)] = vv[dd];
        }
        __syncthreads();

        f32x4 sf[4] = {};
        #pragma unroll
        for (int ni = 0; ni < 4; ni++) {
            bf16x8 bk0 = *(const bf16x8*)&Ks[(ni * 16 + lc) * PSTR + lq * 8];
            bf16x8 bk1 = *(const bf16x8*)&Ks[(ni * 16 + lc) * PSTR + 32 + lq * 8];
            sf[ni] = __builtin_amdgcn_mfma_f32_16x16x32_bf16(aq0, bk0, sf[ni], 0, 0, 0);
            sf[ni] = __builtin_amdgcn_mfma_f32_16x16x32_bf16(aq1, bk1, sf[ni], 0, 0, 0);
        }

        const ushort* bbase = biasb + (size_t)(b * S_ + i0 + wq * 16 + lq * 4) * S_ + j0;
        #pragma unroll
        for (int ni = 0; ni < 4; ni++)
            #pragma unroll
            for (int rr = 0; rr < 4; rr++) {
                float bv = bf2f(bbase[(size_t)rr * S_ + ni * 16 + lc]);
                float p = __builtin_amdgcn_exp2f(fmaf(sf[ni][rr], QSC, bv));
                l_lane[rr] += p;
                Ps[(wq * 16 + lq * 4 + rr) * PSTR + ni * 16 + lc] = f2bf(p);
            }

        bf16x8 ap0 = *(const bf16x8*)&Ps[(wq * 16 + lc) * PSTR + lq * 8];
        bf16x8 ap1 = *(const bf16x8*)&Ps[(wq * 16 + lc) * PSTR + 32 + lq * 8];
        #pragma unroll
        for (int ni = 0; ni < 4; ni++) {
            bf16x8 bv0 = *(const bf16x8*)&Vts[vswz(ni * 16 + lc, lq * 8)];
            bf16x8 bv1 = *(const bf16x8*)&Vts[vswz(ni * 16 + lc, 32 + lq * 8)];
            of[ni] = __builtin_amdgcn_mfma_f32_16x16x32_bf16(ap0, bv0, of[ni], 0, 0, 0);
            of[ni] = __builtin_amdgcn_mfma_f32_16x16x32_bf16(ap1, bv1, of[ni], 0, 0, 0);
        }
    }

    float inv[4];
    #pragma unroll
    for (int rr = 0; rr < 4; rr++) {
        float s = l_lane[rr];
        s += __shfl_xor(s, 1);
        s += __shfl_xor(s, 2);
        s += __shfl_xor(s, 4);
        s += __shfl_xor(s, 8);
        inv[rr] = 1.f / s;
    }
    #pragma unroll
    for (int ni = 0; ni < 4; ni++)
        #pragma unroll
        for (int rr = 0; rr < 4; rr++) {
            int row = i0 + wq * 16 + lq * 4 + rr;
            ao[(size_t)(b * S_ + row) * D_ + h * 64 + ni * 16 + lc] = f2bf(of[ni][rr] * inv[rr]);
        }
}

// ---------------------------------------------------------------------------
// x = LayerNorm(x + p + bvec) * g + b (in place), emits bf16 copy xb
// ---------------------------------------------------------------------------
__device__ __forceinline__ float block_sum(float v, float* red) {
    #pragma unroll
    for (int off = 32; off > 0; off >>= 1) v += __shfl_down(v, off);
    int t = threadIdx.x;
    if ((t & 63) == 0) red[t >> 6] = v;
    __syncthreads();
    float r = red[0] + red[1] + red[2] + red[3];
    __syncthreads();
    return r;
}

__global__ __launch_bounds__(256) void add_ln_kernel(
    float* __restrict__ x, const float* __restrict__ p,
    const float* __restrict__ bvec,
    const float* __restrict__ g, const float* __restrict__ bta,
    ushort* __restrict__ xb)
{
    __shared__ float red[4];
    const int row = blockIdx.x;
    const int t = threadIdx.x;
    const size_t base = (size_t)row * D_;
    float v0 = x[base + t]       + p[base + t]       + bvec[t];
    float v1 = x[base + t + 256] + p[base + t + 256] + bvec[t + 256];
    float mean = block_sum(v0 + v1, red) * (1.f / (float)D_);
    float d0 = v0 - mean, d1 = v1 - mean;
    float var = block_sum(d0 * d0 + d1 * d1, red) * (1.f / (float)D_);
    float inv = rsqrtf(var + 1e-5f);
    float o0 = d0 * inv * g[t] + bta[t];
    float o1 = d1 * inv * g[t + 256] + bta[t + 256];
    x[base + t] = o0;
    x[base + t + 256] = o1;
    xb[base + t] = f2bf(o0);
    xb[base + t + 256] = f2bf(o1);
}

// ---------------------------------------------------------------------------
// logits: grid (B, 8); block handles 128 vocab rows
// ---------------------------------------------------------------------------
__global__ __launch_bounds__(256) void logits_kernel(
    const float* __restrict__ x, const float* __restrict__ lw, float* __restrict__ out)
{
    __shared__ float xs[D_];
    const int b = blockIdx.x;
    const int vchunk = blockIdx.y;
    const int t = threadIdx.x;
    const float* xrow = x + ((size_t)(b * S_ + (S_ - 1)) * D_);
    xs[t] = xrow[t];
    xs[t + 256] = xrow[t + 256];
    __syncthreads();
    for (int vv = vchunk * 128 + t; vv < vchunk * 128 + 128; vv += 256) {
        const float* wr = lw + (size_t)vv * D_;
        float acc = 0.f;
        #pragma unroll 8
        for (int d = 0; d < D_; d += 4) {
            float4 w4 = *(const float4*)&wr[d];
            acc += xs[d] * w4.x + xs[d + 1] * w4.y + xs[d + 2] * w4.z + xs[d + 3] * w4.w;
        }
        out[(size_t)b * VOCAB_ + vv] = acc;
    }
}

// ---------------------------------------------------------------------------
extern "C" void kernel_launch(void* const* d_in, const int* in_sizes, int n_in,
                              void* d_out, int out_size, void* d_ws, size_t ws_size,
                              hipStream_t stream)
{
    const int* raw_x = (const int*)d_in[0];
    const int* sdeg  = (const int*)d_in[1];
    const int* pci   = (const int*)d_in[2];
    const int* pcn   = (const int*)d_in[3];
    const int* sbi   = (const int*)d_in[4];
    const int* sbn   = (const int*)d_in[5];
    const float* vemb = (const float*)d_in[6];
    const float* demb = (const float*)d_in[7];
    const float* arel = (const float*)d_in[8];
    const float* renc = (const float*)d_in[9];
    const float* Wq = (const float*)d_in[10];
    const float* bq = (const float*)d_in[11];
    const float* Wk = (const float*)d_in[12];
    const float* bk = (const float*)d_in[13];
    const float* Wv = (const float*)d_in[14];
    const float* bv = (const float*)d_in[15];
    const float* Wo = (const float*)d_in[16];
    const float* bo = (const float*)d_in[17];
    const float* W1 = (const float*)d_in[18];
    const float* b1 = (const float*)d_in[19];
    const float* W2 = (const float*)d_in[20];
    const float* b2 = (const float*)d_in[21];
    const float* lng = (const float*)d_in[22];
    const float* lnb = (const float*)d_in[23];
    const float* lw  = (const float*)d_in[24];
    float* out = (float*)d_out;

    float* wsf = (float*)d_ws;
    const size_t X = (size_t)BS_ * D_;               // 4,194,304 floats
    float*  x    = wsf;                               // [0, X)
    ushort* xb   = (ushort*)(wsf + X);                // [X, 1.5X)
    ushort* qkvb = (ushort*)(wsf + (X * 3) / 2);      // [1.5X, 3X)  bf16 BS*1536
    ushort* ao   = (ushort*)(wsf + 3 * X);            // [3X, 3.5X)  bf16 BS*512
    ushort* h1   = (ushort*)(wsf + (X * 7) / 2);      // [3.5X, 5.5X) bf16 BS*2048
    float*  proj = wsf + (X * 11) / 2;                // [5.5X, 6.5X) fp32 C
    float*  bias = wsf + (X * 13) / 2;                // [6.5X, 7.5X) fp32 scatter
    ushort* biasb= (ushort*)(wsf + (X * 15) / 2);     // [7.5X, 8X)   bf16 scaled
    ushort* wb   = (ushort*)(wsf + 8 * X);            // weights bf16: 18,874,368 shorts
    ushort* wqkv_b = wb;                              // L*1536*512
    ushort* wo_b   = wb + 4718592;                    // L*512*512
    ushort* w1_b   = wb + 6291456;                    // L*2048*512
    ushort* w2_b   = wb + 12582912;                   // L*512*2048
    float*  bqkv   = wsf + 8 * X + 9437184;           // L*1536 floats

    // --- embeddings ---
    embed_kernel<<<(B_ * S_ * D_) / 256, 256, 0, stream>>>(raw_x, sdeg, vemb, demb, x);
    relnow_kernel<<<B_, D_, 0, stream>>>(pcn, sbn, arel, x);
    cast4_kernel<<<(int)(X / 4 / 256), 256, 0, stream>>>(x, xb, (int)(X / 4));

    // --- attention bias matrix (fp32 scatter -> bf16 log2e-scaled) ---
    hipMemsetAsync(bias, 0, (size_t)B_ * S_ * S_ * sizeof(float), stream);
    bias_scatter_kernel<<<(NPC_ + NS_ + 255) / 256, 256, 0, stream>>>(pci, sbi, renc, bias);
    bias_cast_kernel<<<(B_ * S_ * S_ / 4) / 256, 256, 0, stream>>>(bias, biasb);

    // --- weight prep ---
    pack_qkv_kernel<<<(L_ * 1536 * 512) / 256, 256, 0, stream>>>(Wq, Wk, Wv, wqkv_b);
    pack_bqkv_kernel<<<(L_ * 1536 + 255) / 256, 256, 0, stream>>>(bq, bk, bv, bqkv);
    cast4_kernel<<<(L_ * 512 * 512) / 4 / 256, 256, 0, stream>>>(Wo, wo_b, L_ * 512 * 512 / 4);
    cast4_kernel<<<(L_ * 2048 * 512) / 4 / 256, 256, 0, stream>>>(W1, w1_b, L_ * 2048 * 512 / 4);
    cast4_kernel<<<(L_ * 512 * 2048) / 4 / 256, 256, 0, stream>>>(W2, w2_b, L_ * 512 * 2048 / 4);

    dim3 blk(256);
    for (int l = 0; l < L_; l++) {
        // QKV: (8192,512)x(1536,512)^T -> qkvb bf16
        gemm_bf16<<<dim3(1536 / 128, BS_ / 128), blk, 0, stream>>>(
            xb, wqkv_b + (size_t)l * 1536 * 512, bqkv + l * 1536, qkvb, 512, 1536, 2);

        attn_kernel<<<dim3(S_ / 64, H_, B_), blk, 0, stream>>>(qkvb, biasb, ao);

        // O-proj: 128x64 tiles, 512 blocks, fp32 out
        gemm64<<<dim3(512 / 64, BS_ / 128), blk, 0, stream>>>(
            ao, wo_b + (size_t)l * 512 * 512, proj, 512, 512);
        add_ln_kernel<<<BS_, blk, 0, stream>>>(x, proj, bo + l * 512,
                                               lng + l * D_, lnb + l * D_, xb);

        // FFN1: (8192,512)x(2048,512)^T + relu -> h1 bf16
        gemm_bf16<<<dim3(2048 / 128, BS_ / 128), blk, 0, stream>>>(
            xb, w1_b + (size_t)l * 2048 * 512, b1 + l * 2048, h1, 512, 2048, 1);
        // FFN2: 128x64 tiles, 512 blocks, fp32 out
        gemm64<<<dim3(512 / 64, BS_ / 128), blk, 0, stream>>>(
            h1, w2_b + (size_t)l * 512 * 2048, proj, 2048, 512);
        add_ln_kernel<<<BS_, blk, 0, stream>>>(x, proj, b2 + l * 512,
                                               lng + l * D_, lnb + l * D_, xb);
    }

    logits_kernel<<<dim3(B_, 8), blk, 0, stream>>>(x, lw, out);
}

// Round 7
// 1155.862 us; speedup vs baseline: 1.0558x; 1.0558x over previous
//
#include <hip/hip_runtime.h>
#include <hip/hip_bf16.h>
#include <math.h>

#define B_ 16
#define S_ 512
#define D_ 512
#define H_ 8
#define L_ 6
#define DPH_ 64
#define DFF_ 2048
#define VOCAB_ 1024
#define NPC_ 4096
#define NS_ 4096
#define BS_ (B_ * S_)   // 8192 rows
#define LOG2E 1.4426950408889634f

typedef __attribute__((ext_vector_type(8))) short bf16x8;
typedef __attribute__((ext_vector_type(4))) float f32x4;

__device__ __forceinline__ ushort f2bf(float f) {
    __hip_bfloat16 h = __float2bfloat16(f);
    return __builtin_bit_cast(ushort, h);
}
__device__ __forceinline__ float bf2f(ushort u) {
    unsigned int v = ((unsigned int)u) << 16;
    return __builtin_bit_cast(float, v);
}

// ---------------------------------------------------------------------------
// Embedding
// ---------------------------------------------------------------------------
__global__ __launch_bounds__(256) void embed_kernel(
    const int* __restrict__ raw_x, const int* __restrict__ sdeg,
    const float* __restrict__ vemb, const float* __restrict__ demb,
    float* __restrict__ x)
{
    size_t idx = (size_t)blockIdx.x * 256 + threadIdx.x;
    int d = (int)(idx & (D_ - 1));
    size_t bs = idx >> 9;
    int s = (int)(bs & (S_ - 1));
    int tok = raw_x[bs];
    int dg  = sdeg[bs];
    float e = expf(-(float)(d & ~1) * (9.210340371976184f / (float)D_));
    float ang = (float)s * e;
    float pe = (d & 1) ? cosf(ang) : sinf(ang);
    x[idx] = vemb[(size_t)tok * D_ + d] + pe + demb[(size_t)dg * D_ + d];
}

__global__ void relnow_kernel(const int* __restrict__ pcn, const int* __restrict__ sbn,
                              const float* __restrict__ arel, float* __restrict__ x)
{
    int b = blockIdx.x;
    int t = threadIdx.x;   // 512 threads
    int b1 = pcn[b * 2 + 0], p1 = pcn[b * 2 + 1];
    x[((size_t)(b1 * S_ + p1)) * D_ + t] += arel[t];
    int b2 = sbn[b * 2 + 0], p2 = sbn[b * 2 + 1];
    x[((size_t)(b2 * S_ + p2)) * D_ + t] += arel[D_ + t];
}

__global__ void bias_scatter_kernel(const int* __restrict__ pc, const int* __restrict__ sb,
                                    const float* __restrict__ renc, float* __restrict__ bias)
{
    int t = blockIdx.x * 256 + threadIdx.x;
    float r0 = renc[0], r1 = renc[1], r2 = renc[2];
    if (t < NPC_) {
        int b = pc[t * 3 + 0], i = pc[t * 3 + 1], j = pc[t * 3 + 2];
        atomicAdd(&bias[((size_t)b * S_ + i) * S_ + j], r0);
        atomicAdd(&bias[((size_t)b * S_ + j) * S_ + i], r1);
    } else if (t < NPC_ + NS_) {
        int u = t - NPC_;
        int b = sb[u * 3 + 0], i = sb[u * 3 + 1], j = sb[u * 3 + 2];
        atomicAdd(&bias[((size_t)b * S_ + i) * S_ + j], r2);
        atomicAdd(&bias[((size_t)b * S_ + j) * S_ + i], r2);
    }
}

// bias fp32 -> bf16 scaled by log2(e)
__global__ __launch_bounds__(256) void bias_cast_kernel(const float* __restrict__ src,
                                                        ushort* __restrict__ dst)
{
    int i = blockIdx.x * 256 + threadIdx.x;   // < B*S*S/4
    float4 v = ((const float4*)src)[i];
    ushort4 o;
    o.x = f2bf(v.x * LOG2E); o.y = f2bf(v.y * LOG2E);
    o.z = f2bf(v.z * LOG2E); o.w = f2bf(v.w * LOG2E);
    ((ushort4*)dst)[i] = o;
}

// ---------------------------------------------------------------------------
// Weight prep
// ---------------------------------------------------------------------------
__global__ __launch_bounds__(256) void cast4_kernel(const float* __restrict__ src,
                                                    ushort* __restrict__ dst, int n4)
{
    int i = blockIdx.x * 256 + threadIdx.x;
    if (i >= n4) return;
    float4 v = ((const float4*)src)[i];
    ushort4 o;
    o.x = f2bf(v.x); o.y = f2bf(v.y); o.z = f2bf(v.z); o.w = f2bf(v.w);
    ((ushort4*)dst)[i] = o;
}

__global__ __launch_bounds__(256) void pack_qkv_kernel(
    const float* __restrict__ Wq, const float* __restrict__ Wk, const float* __restrict__ Wv,
    ushort* __restrict__ dst)
{
    int idx = blockIdx.x * 256 + threadIdx.x;   // < L*1536*512
    int c = idx & 511;
    int rl = idx >> 9;
    int r = rl % 1536, l = rl / 1536;
    float v;
    if (r < 512)       v = Wq[((size_t)l * 512 + r) * 512 + c];
    else if (r < 1024) v = Wk[((size_t)l * 512 + (r - 512)) * 512 + c];
    else               v = Wv[((size_t)l * 512 + (r - 1024)) * 512 + c];
    dst[idx] = f2bf(v);
}

__global__ void pack_bqkv_kernel(const float* __restrict__ bq, const float* __restrict__ bk,
                                 const float* __restrict__ bv, float* __restrict__ dst)
{
    int idx = blockIdx.x * 256 + threadIdx.x;
    if (idx >= L_ * 1536) return;
    int r = idx % 1536, l = idx / 1536;
    float v;
    if (r < 512)       v = bq[l * 512 + r];
    else if (r < 1024) v = bk[l * 512 + r - 512];
    else               v = bv[l * 512 + r - 1024];
    dst[idx] = v;
}

// ---------------------------------------------------------------------------
// bf16 MFMA NT GEMM, 128x128 tile, BK=64 via two proven 32-k LDS buffers.
// GRID: blockIdx.x = ROW tile (XCD swizzle: same-row col-blocks land on one
// XCD, sharing the A-strip in its L2), blockIdx.y = COL tile.
// ---------------------------------------------------------------------------
#define GL2LDS(g, l) __builtin_amdgcn_global_load_lds( \
    (const __attribute__((address_space(1))) void*)(g), \
    (__attribute__((address_space(3))) void*)(l), 16, 0, 0)

__global__ __launch_bounds__(256) void gemm_bf16(
    const ushort* __restrict__ A, const ushort* __restrict__ W,
    const float* __restrict__ bias, ushort* __restrict__ Cb,
    int K, int M, int mode)
{
    __shared__ ushort As0[128 * 32];
    __shared__ ushort As1[128 * 32];
    __shared__ ushort Bs0[128 * 32];
    __shared__ ushort Bs1[128 * 32];

    const int t  = threadIdx.x;
    const int wv = t >> 6;
    const int ln = t & 63;
    const int wm = wv >> 1, wn = wv & 1;
    const int lq = ln >> 4, lc = ln & 15;
    const int row0 = blockIdx.x * 128;
    const int col0 = blockIdx.y * 128;
    const int lr = ln >> 2;
    const int lk = (ln & 3) * 8;

    f32x4 acc[4][4] = {};

    for (int k0 = 0; k0 < K; k0 += 64) {
        #pragma unroll
        for (int i = 0; i < 2; i++) {
            int r = i * 64 + wv * 16;
            const ushort* ga = A + (size_t)(row0 + r + lr) * K + k0 + lk;
            const ushort* gb = W + (size_t)(col0 + r + lr) * K + k0 + lk;
            GL2LDS(ga,      &As0[r * 32]);
            GL2LDS(gb,      &Bs0[r * 32]);
            GL2LDS(ga + 32, &As1[r * 32]);
            GL2LDS(gb + 32, &Bs1[r * 32]);
        }
        __syncthreads();

        bf16x8 af[4], bf[4];
        #pragma unroll
        for (int mi = 0; mi < 4; mi++)
            af[mi] = *(const bf16x8*)&As0[(wm * 64 + mi * 16 + lc) * 32 + lq * 8];
        #pragma unroll
        for (int ni = 0; ni < 4; ni++)
            bf[ni] = *(const bf16x8*)&Bs0[(wn * 64 + ni * 16 + lc) * 32 + lq * 8];
        #pragma unroll
        for (int mi = 0; mi < 4; mi++)
            #pragma unroll
            for (int ni = 0; ni < 4; ni++)
                acc[mi][ni] = __builtin_amdgcn_mfma_f32_16x16x32_bf16(af[mi], bf[ni], acc[mi][ni], 0, 0, 0);

        #pragma unroll
        for (int mi = 0; mi < 4; mi++)
            af[mi] = *(const bf16x8*)&As1[(wm * 64 + mi * 16 + lc) * 32 + lq * 8];
        #pragma unroll
        for (int ni = 0; ni < 4; ni++)
            bf[ni] = *(const bf16x8*)&Bs1[(wn * 64 + ni * 16 + lc) * 32 + lq * 8];
        #pragma unroll
        for (int mi = 0; mi < 4; mi++)
            #pragma unroll
            for (int ni = 0; ni < 4; ni++)
                acc[mi][ni] = __builtin_amdgcn_mfma_f32_16x16x32_bf16(af[mi], bf[ni], acc[mi][ni], 0, 0, 0);
        __syncthreads();
    }

    #pragma unroll
    for (int mi = 0; mi < 4; mi++) {
        #pragma unroll
        for (int ni = 0; ni < 4; ni++) {
            int gcol = col0 + wn * 64 + ni * 16 + lc;
            float bb = bias[gcol];
            #pragma unroll
            for (int rr = 0; rr < 4; rr++) {
                int grow = row0 + wm * 64 + mi * 16 + lq * 4 + rr;
                float val = acc[mi][ni][rr] + bb;
                if (mode == 1) val = fmaxf(val, 0.f);
                Cb[(size_t)grow * M + gcol] = f2bf(val);
            }
        }
    }
}

// ---------------------------------------------------------------------------
// 128-row x 64-col tile, full-K, fp32 out (bias folded into add_ln).
// GRID: x = ROW tile (64), y = COL tile (8). All 8 col-blocks of a row-strip
// have linear IDs = x (mod 8) -> same XCD; 512 blocks = 2/CU so an XCD's
// 64 blocks (8 strips x 8 cols) are co-resident: 8 x 512KB A-strips = 4MB L2.
// ---------------------------------------------------------------------------
__global__ __launch_bounds__(256) void gemm64(
    const ushort* __restrict__ A, const ushort* __restrict__ W,
    float* __restrict__ C, int K, int M)
{
    __shared__ ushort As0[128 * 32];
    __shared__ ushort As1[128 * 32];
    __shared__ ushort Bs0[64 * 32];
    __shared__ ushort Bs1[64 * 32];

    const int t  = threadIdx.x;
    const int wv = t >> 6;
    const int ln = t & 63;
    const int wm = wv >> 1, wn = wv & 1;
    const int lq = ln >> 4, lc = ln & 15;
    const int row0 = blockIdx.x * 128;
    const int col0 = blockIdx.y * 64;
    const int lr = ln >> 2;
    const int lk = (ln & 3) * 8;

    f32x4 acc[4][2] = {};

    for (int k0 = 0; k0 < K; k0 += 64) {
        #pragma unroll
        for (int i = 0; i < 2; i++) {
            int r = i * 64 + wv * 16;
            const ushort* ga = A + (size_t)(row0 + r + lr) * K + k0 + lk;
            GL2LDS(ga,      &As0[r * 32]);
            GL2LDS(ga + 32, &As1[r * 32]);
        }
        {
            int rb = wv * 16;
            const ushort* gb = W + (size_t)(col0 + rb + lr) * K + k0 + lk;
            GL2LDS(gb,      &Bs0[rb * 32]);
            GL2LDS(gb + 32, &Bs1[rb * 32]);
        }
        __syncthreads();

        bf16x8 af[4], bf[2];
        #pragma unroll
        for (int mi = 0; mi < 4; mi++)
            af[mi] = *(const bf16x8*)&As0[(wm * 64 + mi * 16 + lc) * 32 + lq * 8];
        #pragma unroll
        for (int ni = 0; ni < 2; ni++)
            bf[ni] = *(const bf16x8*)&Bs0[(wn * 32 + ni * 16 + lc) * 32 + lq * 8];
        #pragma unroll
        for (int mi = 0; mi < 4; mi++)
            #pragma unroll
            for (int ni = 0; ni < 2; ni++)
                acc[mi][ni] = __builtin_amdgcn_mfma_f32_16x16x32_bf16(af[mi], bf[ni], acc[mi][ni], 0, 0, 0);

        #pragma unroll
        for (int mi = 0; mi < 4; mi++)
            af[mi] = *(const bf16x8*)&As1[(wm * 64 + mi * 16 + lc) * 32 + lq * 8];
        #pragma unroll
        for (int ni = 0; ni < 2; ni++)
            bf[ni] = *(const bf16x8*)&Bs1[(wn * 32 + ni * 16 + lc) * 32 + lq * 8];
        #pragma unroll
        for (int mi = 0; mi < 4; mi++)
            #pragma unroll
            for (int ni = 0; ni < 2; ni++)
                acc[mi][ni] = __builtin_amdgcn_mfma_f32_16x16x32_bf16(af[mi], bf[ni], acc[mi][ni], 0, 0, 0);
        __syncthreads();
    }

    #pragma unroll
    for (int mi = 0; mi < 4; mi++)
        #pragma unroll
        for (int ni = 0; ni < 2; ni++) {
            int gcol = col0 + wn * 32 + ni * 16 + lc;
            #pragma unroll
            for (int rr = 0; rr < 4; rr++) {
                int grow = row0 + wm * 64 + mi * 16 + lq * 4 + rr;
                C[(size_t)grow * M + gcol] = acc[mi][ni][rr];
            }
        }
}

// ---------------------------------------------------------------------------
// MFMA flash attention, no-max softmax (unchanged)
// ---------------------------------------------------------------------------
#define PSTR 72

__device__ __forceinline__ int vswz(int d, int j) {
    int g = ((j >> 3) ^ (d & 7) ^ ((d >> 3) & 7)) & 7;
    return d * 64 + g * 8 + (j & 7);
}

__global__ __launch_bounds__(256) void attn_kernel(
    const ushort* __restrict__ qkv, const ushort* __restrict__ biasb,
    ushort* __restrict__ ao)
{
    const int qt = blockIdx.x, h = blockIdx.y, b = blockIdx.z;
    const int t  = threadIdx.x;
    const int wq = t >> 6;
    const int ln = t & 63;
    const int lq = ln >> 4;
    const int lc = ln & 15;
    const int r  = t >> 2;
    const int cg = t & 3;

    __shared__ ushort Qs[64 * PSTR];
    __shared__ ushort Ks[64 * PSTR];
    __shared__ ushort Ps[64 * PSTR];
    __shared__ ushort Vts[64 * 64];

    const int i0 = qt * 64;

    {
        const ushort* qsrc = qkv + (size_t)(b * S_ + i0 + r) * 1536 + h * 64 + cg * 16;
        *(uint4*)&Qs[r * PSTR + cg * 16]     = ((const uint4*)qsrc)[0];
        *(uint4*)&Qs[r * PSTR + cg * 16 + 8] = ((const uint4*)qsrc)[1];
    }
    bf16x8 aq0 = *(const bf16x8*)&Qs[(wq * 16 + lc) * PSTR + lq * 8];
    bf16x8 aq1 = *(const bf16x8*)&Qs[(wq * 16 + lc) * PSTR + 32 + lq * 8];

    f32x4 of[4] = {};
    float l_lane[4] = {};
    const float QSC = 0.125f * LOG2E;

    for (int j0 = 0; j0 < S_; j0 += 64) {
        __syncthreads();
        {
            const ushort* ksrc = qkv + (size_t)(b * S_ + j0 + r) * 1536 + 512 + h * 64 + cg * 16;
            *(uint4*)&Ks[r * PSTR + cg * 16]     = ((const uint4*)ksrc)[0];
            *(uint4*)&Ks[r * PSTR + cg * 16 + 8] = ((const uint4*)ksrc)[1];
            const ushort* vsrc = ksrc + 512;
            ushort vv[16];
            *(uint4*)&vv[0] = ((const uint4*)vsrc)[0];
            *(uint4*)&vv[8] = ((const uint4*)vsrc)[1];
            #pragma unroll
            for (int dd = 0; dd < 16; dd++)
                Vts[vswz(cg * 16 + dd, r)] = vv[dd];
        }
        __syncthreads();

        f32x4 sf[4] = {};
        #pragma unroll
        for (int ni = 0; ni < 4; ni++) {
            bf16x8 bk0 = *(const bf16x8*)&Ks[(ni * 16 + lc) * PSTR + lq * 8];
            bf16x8 bk1 = *(const bf16x8*)&Ks[(ni * 16 + lc) * PSTR + 32 + lq * 8];
            sf[ni] = __builtin_amdgcn_mfma_f32_16x16x32_bf16(aq0, bk0, sf[ni], 0, 0, 0);
            sf[ni] = __builtin_amdgcn_mfma_f32_16x16x32_bf16(aq1, bk1, sf[ni], 0, 0, 0);
        }

        const ushort* bbase = biasb + (size_t)(b * S_ + i0 + wq * 16 + lq * 4) * S_ + j0;
        #pragma unroll
        for (int ni = 0; ni < 4; ni++)
            #pragma unroll
            for (int rr = 0; rr < 4; rr++) {
                float bv = bf2f(bbase[(size_t)rr * S_ + ni * 16 + lc]);
                float p = __builtin_amdgcn_exp2f(fmaf(sf[ni][rr], QSC, bv));
                l_lane[rr] += p;
                Ps[(wq * 16 + lq * 4 + rr) * PSTR + ni * 16 + lc] = f2bf(p);
            }

        bf16x8 ap0 = *(const bf16x8*)&Ps[(wq * 16 + lc) * PSTR + lq * 8];
        bf16x8 ap1 = *(const bf16x8*)&Ps[(wq * 16 + lc) * PSTR + 32 + lq * 8];
        #pragma unroll
        for (int ni = 0; ni < 4; ni++) {
            bf16x8 bv0 = *(const bf16x8*)&Vts[vswz(ni * 16 + lc, lq * 8)];
            bf16x8 bv1 = *(const bf16x8*)&Vts[vswz(ni * 16 + lc, 32 + lq * 8)];
            of[ni] = __builtin_amdgcn_mfma_f32_16x16x32_bf16(ap0, bv0, of[ni], 0, 0, 0);
            of[ni] = __builtin_amdgcn_mfma_f32_16x16x32_bf16(ap1, bv1, of[ni], 0, 0, 0);
        }
    }

    float inv[4];
    #pragma unroll
    for (int rr = 0; rr < 4; rr++) {
        float s = l_lane[rr];
        s += __shfl_xor(s, 1);
        s += __shfl_xor(s, 2);
        s += __shfl_xor(s, 4);
        s += __shfl_xor(s, 8);
        inv[rr] = 1.f / s;
    }
    #pragma unroll
    for (int ni = 0; ni < 4; ni++)
        #pragma unroll
        for (int rr = 0; rr < 4; rr++) {
            int row = i0 + wq * 16 + lq * 4 + rr;
            ao[(size_t)(b * S_ + row) * D_ + h * 64 + ni * 16 + lc] = f2bf(of[ni][rr] * inv[rr]);
        }
}

// ---------------------------------------------------------------------------
// x = LayerNorm(x + p + bvec) * g + b (in place), emits bf16 copy xb
// ---------------------------------------------------------------------------
__device__ __forceinline__ float block_sum(float v, float* red) {
    #pragma unroll
    for (int off = 32; off > 0; off >>= 1) v += __shfl_down(v, off);
    int t = threadIdx.x;
    if ((t & 63) == 0) red[t >> 6] = v;
    __syncthreads();
    float r = red[0] + red[1] + red[2] + red[3];
    __syncthreads();
    return r;
}

__global__ __launch_bounds__(256) void add_ln_kernel(
    float* __restrict__ x, const float* __restrict__ p,
    const float* __restrict__ bvec,
    const float* __restrict__ g, const float* __restrict__ bta,
    ushort* __restrict__ xb)
{
    __shared__ float red[4];
    const int row = blockIdx.x;
    const int t = threadIdx.x;
    const size_t base = (size_t)row * D_;
    float v0 = x[base + t]       + p[base + t]       + bvec[t];
    float v1 = x[base + t + 256] + p[base + t + 256] + bvec[t + 256];
    float mean = block_sum(v0 + v1, red) * (1.f / (float)D_);
    float d0 = v0 - mean, d1 = v1 - mean;
    float var = block_sum(d0 * d0 + d1 * d1, red) * (1.f / (float)D_);
    float inv = rsqrtf(var + 1e-5f);
    float o0 = d0 * inv * g[t] + bta[t];
    float o1 = d1 * inv * g[t + 256] + bta[t + 256];
    x[base + t] = o0;
    x[base + t + 256] = o1;
    xb[base + t] = f2bf(o0);
    xb[base + t + 256] = f2bf(o1);
}

// ---------------------------------------------------------------------------
// logits: grid (B, 8); block handles 128 vocab rows
// ---------------------------------------------------------------------------
__global__ __launch_bounds__(256) void logits_kernel(
    const float* __restrict__ x, const float* __restrict__ lw, float* __restrict__ out)
{
    __shared__ float xs[D_];
    const int b = blockIdx.x;
    const int vchunk = blockIdx.y;
    const int t = threadIdx.x;
    const float* xrow = x + ((size_t)(b * S_ + (S_ - 1)) * D_);
    xs[t] = xrow[t];
    xs[t + 256] = xrow[t + 256];
    __syncthreads();
    for (int vv = vchunk * 128 + t; vv < vchunk * 128 + 128; vv += 256) {
        const float* wr = lw + (size_t)vv * D_;
        float acc = 0.f;
        #pragma unroll 8
        for (int d = 0; d < D_; d += 4) {
            float4 w4 = *(const float4*)&wr[d];
            acc += xs[d] * w4.x + xs[d + 1] * w4.y + xs[d + 2] * w4.z + xs[d + 3] * w4.w;
        }
        out[(size_t)b * VOCAB_ + vv] = acc;
    }
}

// ---------------------------------------------------------------------------
extern "C" void kernel_launch(void* const* d_in, const int* in_sizes, int n_in,
                              void* d_out, int out_size, void* d_ws, size_t ws_size,
                              hipStream_t stream)
{
    const int* raw_x = (const int*)d_in[0];
    const int* sdeg  = (const int*)d_in[1];
    const int* pci   = (const int*)d_in[2];
    const int* pcn   = (const int*)d_in[3];
    const int* sbi   = (const int*)d_in[4];
    const int* sbn   = (const int*)d_in[5];
    const float* vemb = (const float*)d_in[6];
    const float* demb = (const float*)d_in[7];
    const float* arel = (const float*)d_in[8];
    const float* renc = (const float*)d_in[9];
    const float* Wq = (const float*)d_in[10];
    const float* bq = (const float*)d_in[11];
    const float* Wk = (const float*)d_in[12];
    const float* bk = (const float*)d_in[13];
    const float* Wv = (const float*)d_in[14];
    const float* bv = (const float*)d_in[15];
    const float* Wo = (const float*)d_in[16];
    const float* bo = (const float*)d_in[17];
    const float* W1 = (const float*)d_in[18];
    const float* b1 = (const float*)d_in[19];
    const float* W2 = (const float*)d_in[20];
    const float* b2 = (const float*)d_in[21];
    const float* lng = (const float*)d_in[22];
    const float* lnb = (const float*)d_in[23];
    const float* lw  = (const float*)d_in[24];
    float* out = (float*)d_out;

    float* wsf = (float*)d_ws;
    const size_t X = (size_t)BS_ * D_;               // 4,194,304 floats
    float*  x    = wsf;                               // [0, X)
    ushort* xb   = (ushort*)(wsf + X);                // [X, 1.5X)
    ushort* qkvb = (ushort*)(wsf + (X * 3) / 2);      // [1.5X, 3X)  bf16 BS*1536
    ushort* ao   = (ushort*)(wsf + 3 * X);            // [3X, 3.5X)  bf16 BS*512
    ushort* h1   = (ushort*)(wsf + (X * 7) / 2);      // [3.5X, 5.5X) bf16 BS*2048
    float*  proj = wsf + (X * 11) / 2;                // [5.5X, 6.5X) fp32 C
    float*  bias = wsf + (X * 13) / 2;                // [6.5X, 7.5X) fp32 scatter
    ushort* biasb= (ushort*)(wsf + (X * 15) / 2);     // [7.5X, 8X)   bf16 scaled
    ushort* wb   = (ushort*)(wsf + 8 * X);            // weights bf16: 18,874,368 shorts
    ushort* wqkv_b = wb;                              // L*1536*512
    ushort* wo_b   = wb + 4718592;                    // L*512*512
    ushort* w1_b   = wb + 6291456;                    // L*2048*512
    ushort* w2_b   = wb + 12582912;                   // L*512*2048
    float*  bqkv   = wsf + 8 * X + 9437184;           // L*1536 floats

    // --- embeddings ---
    embed_kernel<<<(B_ * S_ * D_) / 256, 256, 0, stream>>>(raw_x, sdeg, vemb, demb, x);
    relnow_kernel<<<B_, D_, 0, stream>>>(pcn, sbn, arel, x);
    cast4_kernel<<<(int)(X / 4 / 256), 256, 0, stream>>>(x, xb, (int)(X / 4));

    // --- attention bias matrix (fp32 scatter -> bf16 log2e-scaled) ---
    hipMemsetAsync(bias, 0, (size_t)B_ * S_ * S_ * sizeof(float), stream);
    bias_scatter_kernel<<<(NPC_ + NS_ + 255) / 256, 256, 0, stream>>>(pci, sbi, renc, bias);
    bias_cast_kernel<<<(B_ * S_ * S_ / 4) / 256, 256, 0, stream>>>(bias, biasb);

    // --- weight prep ---
    pack_qkv_kernel<<<(L_ * 1536 * 512) / 256, 256, 0, stream>>>(Wq, Wk, Wv, wqkv_b);
    pack_bqkv_kernel<<<(L_ * 1536 + 255) / 256, 256, 0, stream>>>(bq, bk, bv, bqkv);
    cast4_kernel<<<(L_ * 512 * 512) / 4 / 256, 256, 0, stream>>>(Wo, wo_b, L_ * 512 * 512 / 4);
    cast4_kernel<<<(L_ * 2048 * 512) / 4 / 256, 256, 0, stream>>>(W1, w1_b, L_ * 2048 * 512 / 4);
    cast4_kernel<<<(L_ * 512 * 2048) / 4 / 256, 256, 0, stream>>>(W2, w2_b, L_ * 512 * 2048 / 4);

    dim3 blk(256);
    for (int l = 0; l < L_; l++) {
        // QKV: grid x=rows(64), y=cols(12)
        gemm_bf16<<<dim3(BS_ / 128, 1536 / 128), blk, 0, stream>>>(
            xb, wqkv_b + (size_t)l * 1536 * 512, bqkv + l * 1536, qkvb, 512, 1536, 2);

        attn_kernel<<<dim3(S_ / 64, H_, B_), blk, 0, stream>>>(qkvb, biasb, ao);

        // O-proj: grid x=rows(64), y=cols(8)
        gemm64<<<dim3(BS_ / 128, 512 / 64), blk, 0, stream>>>(
            ao, wo_b + (size_t)l * 512 * 512, proj, 512, 512);
        add_ln_kernel<<<BS_, blk, 0, stream>>>(x, proj, bo + l * 512,
                                               lng + l * D_, lnb + l * D_, xb);

        // FFN1: grid x=rows(64), y=cols(16)
        gemm_bf16<<<dim3(BS_ / 128, 2048 / 128), blk, 0, stream>>>(
            xb, w1_b + (size_t)l * 2048 * 512, b1 + l * 2048, h1, 512, 2048, 1);
        // FFN2: grid x=rows(64), y=cols(8)
        gemm64<<<dim3(BS_ / 128, 512 / 64), blk, 0, stream>>>(
            h1, w2_b + (size_t)l * 512 * 2048, proj, 2048, 512);
        add_ln_kernel<<<BS_, blk, 0, stream>>>(x, proj, b2 + l * 512,
                                               lng + l * D_, lnb + l * D_, xb);
    }

    logits_kernel<<<dim3(B_, 8), blk, 0, stream>>>(x, lw, out);
}

// Round 8
// 1082.190 us; speedup vs baseline: 1.1277x; 1.0681x over previous
//
#include <hip/hip_runtime.h>
#include <hip/hip_bf16.h>
#include <math.h>

#define B_ 16
#define S_ 512
#define D_ 512
#define H_ 8
#define L_ 6
#define DPH_ 64
#define DFF_ 2048
#define VOCAB_ 1024
#define NPC_ 4096
#define NS_ 4096
#define BS_ (B_ * S_)   // 8192 rows
#define LOG2E 1.4426950408889634f

typedef __attribute__((ext_vector_type(8))) short bf16x8;
typedef __attribute__((ext_vector_type(4))) float f32x4;

__device__ __forceinline__ ushort f2bf(float f) {
    __hip_bfloat16 h = __float2bfloat16(f);
    return __builtin_bit_cast(ushort, h);
}
__device__ __forceinline__ float bf2f(ushort u) {
    unsigned int v = ((unsigned int)u) << 16;
    return __builtin_bit_cast(float, v);
}

// ---------------------------------------------------------------------------
// Embedding -> bf16 xb directly (fp32 residual eliminated; LN re-normalizes
// each layer so bf16 residual rounding does not compound)
// ---------------------------------------------------------------------------
__global__ __launch_bounds__(256) void embed_kernel(
    const int* __restrict__ raw_x, const int* __restrict__ sdeg,
    const float* __restrict__ vemb, const float* __restrict__ demb,
    ushort* __restrict__ xb)
{
    size_t idx = (size_t)blockIdx.x * 256 + threadIdx.x;
    int d = (int)(idx & (D_ - 1));
    size_t bs = idx >> 9;
    int s = (int)(bs & (S_ - 1));
    int tok = raw_x[bs];
    int dg  = sdeg[bs];
    float e = expf(-(float)(d & ~1) * (9.210340371976184f / (float)D_));
    float ang = (float)s * e;
    float pe = (d & 1) ? cosf(ang) : sinf(ang);
    xb[idx] = f2bf(vemb[(size_t)tok * D_ + d] + pe + demb[(size_t)dg * D_ + d]);
}

// bf16 read-modify-write of the two "now" rows per batch
__global__ void relnow_kernel(const int* __restrict__ pcn, const int* __restrict__ sbn,
                              const float* __restrict__ arel, ushort* __restrict__ xb)
{
    int b = blockIdx.x;
    int t = threadIdx.x;   // 512 threads
    int b1 = pcn[b * 2 + 0], p1 = pcn[b * 2 + 1];
    size_t i1 = ((size_t)(b1 * S_ + p1)) * D_ + t;
    xb[i1] = f2bf(bf2f(xb[i1]) + arel[t]);
    int b2 = sbn[b * 2 + 0], p2 = sbn[b * 2 + 1];
    size_t i2 = ((size_t)(b2 * S_ + p2)) * D_ + t;
    xb[i2] = f2bf(bf2f(xb[i2]) + arel[D_ + t]);
}

__global__ void bias_scatter_kernel(const int* __restrict__ pc, const int* __restrict__ sb,
                                    const float* __restrict__ renc, float* __restrict__ bias)
{
    int t = blockIdx.x * 256 + threadIdx.x;
    float r0 = renc[0], r1 = renc[1], r2 = renc[2];
    if (t < NPC_) {
        int b = pc[t * 3 + 0], i = pc[t * 3 + 1], j = pc[t * 3 + 2];
        atomicAdd(&bias[((size_t)b * S_ + i) * S_ + j], r0);
        atomicAdd(&bias[((size_t)b * S_ + j) * S_ + i], r1);
    } else if (t < NPC_ + NS_) {
        int u = t - NPC_;
        int b = sb[u * 3 + 0], i = sb[u * 3 + 1], j = sb[u * 3 + 2];
        atomicAdd(&bias[((size_t)b * S_ + i) * S_ + j], r2);
        atomicAdd(&bias[((size_t)b * S_ + j) * S_ + i], r2);
    }
}

// bias fp32 -> bf16 scaled by log2(e)
__global__ __launch_bounds__(256) void bias_cast_kernel(const float* __restrict__ src,
                                                        ushort* __restrict__ dst)
{
    int i = blockIdx.x * 256 + threadIdx.x;   // < B*S*S/4
    float4 v = ((const float4*)src)[i];
    ushort4 o;
    o.x = f2bf(v.x * LOG2E); o.y = f2bf(v.y * LOG2E);
    o.z = f2bf(v.z * LOG2E); o.w = f2bf(v.w * LOG2E);
    ((ushort4*)dst)[i] = o;
}

// ---------------------------------------------------------------------------
// Weight prep
// ---------------------------------------------------------------------------
__global__ __launch_bounds__(256) void cast4_kernel(const float* __restrict__ src,
                                                    ushort* __restrict__ dst, int n4)
{
    int i = blockIdx.x * 256 + threadIdx.x;
    if (i >= n4) return;
    float4 v = ((const float4*)src)[i];
    ushort4 o;
    o.x = f2bf(v.x); o.y = f2bf(v.y); o.z = f2bf(v.z); o.w = f2bf(v.w);
    ((ushort4*)dst)[i] = o;
}

__global__ __launch_bounds__(256) void pack_qkv_kernel(
    const float* __restrict__ Wq, const float* __restrict__ Wk, const float* __restrict__ Wv,
    ushort* __restrict__ dst)
{
    int idx = blockIdx.x * 256 + threadIdx.x;   // < L*1536*512
    int c = idx & 511;
    int rl = idx >> 9;
    int r = rl % 1536, l = rl / 1536;
    float v;
    if (r < 512)       v = Wq[((size_t)l * 512 + r) * 512 + c];
    else if (r < 1024) v = Wk[((size_t)l * 512 + (r - 512)) * 512 + c];
    else               v = Wv[((size_t)l * 512 + (r - 1024)) * 512 + c];
    dst[idx] = f2bf(v);
}

__global__ void pack_bqkv_kernel(const float* __restrict__ bq, const float* __restrict__ bk,
                                 const float* __restrict__ bv, float* __restrict__ dst)
{
    int idx = blockIdx.x * 256 + threadIdx.x;
    if (idx >= L_ * 1536) return;
    int r = idx % 1536, l = idx / 1536;
    float v;
    if (r < 512)       v = bq[l * 512 + r];
    else if (r < 1024) v = bk[l * 512 + r - 512];
    else               v = bv[l * 512 + r - 1024];
    dst[idx] = v;
}

// ---------------------------------------------------------------------------
// bf16 MFMA NT GEMM, 128x128 tile, BK=64. Grid: x=ROW tile (XCD swizzle),
// y=COL tile. mode 1: bf16+relu. mode 2: bf16.
// ---------------------------------------------------------------------------
#define GL2LDS(g, l) __builtin_amdgcn_global_load_lds( \
    (const __attribute__((address_space(1))) void*)(g), \
    (__attribute__((address_space(3))) void*)(l), 16, 0, 0)

__global__ __launch_bounds__(256) void gemm_bf16(
    const ushort* __restrict__ A, const ushort* __restrict__ W,
    const float* __restrict__ bias, ushort* __restrict__ Cb,
    int K, int M, int mode)
{
    __shared__ ushort As0[128 * 32];
    __shared__ ushort As1[128 * 32];
    __shared__ ushort Bs0[128 * 32];
    __shared__ ushort Bs1[128 * 32];

    const int t  = threadIdx.x;
    const int wv = t >> 6;
    const int ln = t & 63;
    const int wm = wv >> 1, wn = wv & 1;
    const int lq = ln >> 4, lc = ln & 15;
    const int row0 = blockIdx.x * 128;
    const int col0 = blockIdx.y * 128;
    const int lr = ln >> 2;
    const int lk = (ln & 3) * 8;

    f32x4 acc[4][4] = {};

    for (int k0 = 0; k0 < K; k0 += 64) {
        #pragma unroll
        for (int i = 0; i < 2; i++) {
            int r = i * 64 + wv * 16;
            const ushort* ga = A + (size_t)(row0 + r + lr) * K + k0 + lk;
            const ushort* gb = W + (size_t)(col0 + r + lr) * K + k0 + lk;
            GL2LDS(ga,      &As0[r * 32]);
            GL2LDS(gb,      &Bs0[r * 32]);
            GL2LDS(ga + 32, &As1[r * 32]);
            GL2LDS(gb + 32, &Bs1[r * 32]);
        }
        __syncthreads();

        bf16x8 af[4], bf[4];
        #pragma unroll
        for (int mi = 0; mi < 4; mi++)
            af[mi] = *(const bf16x8*)&As0[(wm * 64 + mi * 16 + lc) * 32 + lq * 8];
        #pragma unroll
        for (int ni = 0; ni < 4; ni++)
            bf[ni] = *(const bf16x8*)&Bs0[(wn * 64 + ni * 16 + lc) * 32 + lq * 8];
        #pragma unroll
        for (int mi = 0; mi < 4; mi++)
            #pragma unroll
            for (int ni = 0; ni < 4; ni++)
                acc[mi][ni] = __builtin_amdgcn_mfma_f32_16x16x32_bf16(af[mi], bf[ni], acc[mi][ni], 0, 0, 0);

        #pragma unroll
        for (int mi = 0; mi < 4; mi++)
            af[mi] = *(const bf16x8*)&As1[(wm * 64 + mi * 16 + lc) * 32 + lq * 8];
        #pragma unroll
        for (int ni = 0; ni < 4; ni++)
            bf[ni] = *(const bf16x8*)&Bs1[(wn * 64 + ni * 16 + lc) * 32 + lq * 8];
        #pragma unroll
        for (int mi = 0; mi < 4; mi++)
            #pragma unroll
            for (int ni = 0; ni < 4; ni++)
                acc[mi][ni] = __builtin_amdgcn_mfma_f32_16x16x32_bf16(af[mi], bf[ni], acc[mi][ni], 0, 0, 0);
        __syncthreads();
    }

    #pragma unroll
    for (int mi = 0; mi < 4; mi++) {
        #pragma unroll
        for (int ni = 0; ni < 4; ni++) {
            int gcol = col0 + wn * 64 + ni * 16 + lc;
            float bb = bias[gcol];
            #pragma unroll
            for (int rr = 0; rr < 4; rr++) {
                int grow = row0 + wm * 64 + mi * 16 + lq * 4 + rr;
                float val = acc[mi][ni][rr] + bb;
                if (mode == 1) val = fmaxf(val, 0.f);
                Cb[(size_t)grow * M + gcol] = f2bf(val);
            }
        }
    }
}

// ---------------------------------------------------------------------------
// 128-row x 64-col tile, full-K, bf16 out (no bias — folded into add_ln).
// Grid: x = ROW tile (64), y = COL tile (8); XCD-swizzled for A-strip reuse.
// ---------------------------------------------------------------------------
__global__ __launch_bounds__(256) void gemm64(
    const ushort* __restrict__ A, const ushort* __restrict__ W,
    ushort* __restrict__ Cb, int K, int M)
{
    __shared__ ushort As0[128 * 32];
    __shared__ ushort As1[128 * 32];
    __shared__ ushort Bs0[64 * 32];
    __shared__ ushort Bs1[64 * 32];

    const int t  = threadIdx.x;
    const int wv = t >> 6;
    const int ln = t & 63;
    const int wm = wv >> 1, wn = wv & 1;
    const int lq = ln >> 4, lc = ln & 15;
    const int row0 = blockIdx.x * 128;
    const int col0 = blockIdx.y * 64;
    const int lr = ln >> 2;
    const int lk = (ln & 3) * 8;

    f32x4 acc[4][2] = {};

    for (int k0 = 0; k0 < K; k0 += 64) {
        #pragma unroll
        for (int i = 0; i < 2; i++) {
            int r = i * 64 + wv * 16;
            const ushort* ga = A + (size_t)(row0 + r + lr) * K + k0 + lk;
            GL2LDS(ga,      &As0[r * 32]);
            GL2LDS(ga + 32, &As1[r * 32]);
        }
        {
            int rb = wv * 16;
            const ushort* gb = W + (size_t)(col0 + rb + lr) * K + k0 + lk;
            GL2LDS(gb,      &Bs0[rb * 32]);
            GL2LDS(gb + 32, &Bs1[rb * 32]);
        }
        __syncthreads();

        bf16x8 af[4], bf[2];
        #pragma unroll
        for (int mi = 0; mi < 4; mi++)
            af[mi] = *(const bf16x8*)&As0[(wm * 64 + mi * 16 + lc) * 32 + lq * 8];
        #pragma unroll
        for (int ni = 0; ni < 2; ni++)
            bf[ni] = *(const bf16x8*)&Bs0[(wn * 32 + ni * 16 + lc) * 32 + lq * 8];
        #pragma unroll
        for (int mi = 0; mi < 4; mi++)
            #pragma unroll
            for (int ni = 0; ni < 2; ni++)
                acc[mi][ni] = __builtin_amdgcn_mfma_f32_16x16x32_bf16(af[mi], bf[ni], acc[mi][ni], 0, 0, 0);

        #pragma unroll
        for (int mi = 0; mi < 4; mi++)
            af[mi] = *(const bf16x8*)&As1[(wm * 64 + mi * 16 + lc) * 32 + lq * 8];
        #pragma unroll
        for (int ni = 0; ni < 2; ni++)
            bf[ni] = *(const bf16x8*)&Bs1[(wn * 32 + ni * 16 + lc) * 32 + lq * 8];
        #pragma unroll
        for (int mi = 0; mi < 4; mi++)
            #pragma unroll
            for (int ni = 0; ni < 2; ni++)
                acc[mi][ni] = __builtin_amdgcn_mfma_f32_16x16x32_bf16(af[mi], bf[ni], acc[mi][ni], 0, 0, 0);
        __syncthreads();
    }

    #pragma unroll
    for (int mi = 0; mi < 4; mi++)
        #pragma unroll
        for (int ni = 0; ni < 2; ni++) {
            int gcol = col0 + wn * 32 + ni * 16 + lc;
            #pragma unroll
            for (int rr = 0; rr < 4; rr++) {
                int grow = row0 + wm * 64 + mi * 16 + lq * 4 + rr;
                Cb[(size_t)grow * M + gcol] = f2bf(acc[mi][ni][rr]);
            }
        }
}

// ---------------------------------------------------------------------------
// MFMA flash attention, no-max softmax (unchanged)
// ---------------------------------------------------------------------------
#define PSTR 72

__device__ __forceinline__ int vswz(int d, int j) {
    int g = ((j >> 3) ^ (d & 7) ^ ((d >> 3) & 7)) & 7;
    return d * 64 + g * 8 + (j & 7);
}

__global__ __launch_bounds__(256) void attn_kernel(
    const ushort* __restrict__ qkv, const ushort* __restrict__ biasb,
    ushort* __restrict__ ao)
{
    const int qt = blockIdx.x, h = blockIdx.y, b = blockIdx.z;
    const int t  = threadIdx.x;
    const int wq = t >> 6;
    const int ln = t & 63;
    const int lq = ln >> 4;
    const int lc = ln & 15;
    const int r  = t >> 2;
    const int cg = t & 3;

    __shared__ ushort Qs[64 * PSTR];
    __shared__ ushort Ks[64 * PSTR];
    __shared__ ushort Ps[64 * PSTR];
    __shared__ ushort Vts[64 * 64];

    const int i0 = qt * 64;

    {
        const ushort* qsrc = qkv + (size_t)(b * S_ + i0 + r) * 1536 + h * 64 + cg * 16;
        *(uint4*)&Qs[r * PSTR + cg * 16]     = ((const uint4*)qsrc)[0];
        *(uint4*)&Qs[r * PSTR + cg * 16 + 8] = ((const uint4*)qsrc)[1];
    }
    bf16x8 aq0 = *(const bf16x8*)&Qs[(wq * 16 + lc) * PSTR + lq * 8];
    bf16x8 aq1 = *(const bf16x8*)&Qs[(wq * 16 + lc) * PSTR + 32 + lq * 8];

    f32x4 of[4] = {};
    float l_lane[4] = {};
    const float QSC = 0.125f * LOG2E;

    for (int j0 = 0; j0 < S_; j0 += 64) {
        __syncthreads();
        {
            const ushort* ksrc = qkv + (size_t)(b * S_ + j0 + r) * 1536 + 512 + h * 64 + cg * 16;
            *(uint4*)&Ks[r * PSTR + cg * 16]     = ((const uint4*)ksrc)[0];
            *(uint4*)&Ks[r * PSTR + cg * 16 + 8] = ((const uint4*)ksrc)[1];
            const ushort* vsrc = ksrc + 512;
            ushort vv[16];
            *(uint4*)&vv[0] = ((const uint4*)vsrc)[0];
            *(uint4*)&vv[8] = ((const uint4*)vsrc)[1];
            #pragma unroll
            for (int dd = 0; dd < 16; dd++)
                Vts[vswz(cg * 16 + dd, r)] = vv[dd];
        }
        __syncthreads();

        f32x4 sf[4] = {};
        #pragma unroll
        for (int ni = 0; ni < 4; ni++) {
            bf16x8 bk0 = *(const bf16x8*)&Ks[(ni * 16 + lc) * PSTR + lq * 8];
            bf16x8 bk1 = *(const bf16x8*)&Ks[(ni * 16 + lc) * PSTR + 32 + lq * 8];
            sf[ni] = __builtin_amdgcn_mfma_f32_16x16x32_bf16(aq0, bk0, sf[ni], 0, 0, 0);
            sf[ni] = __builtin_amdgcn_mfma_f32_16x16x32_bf16(aq1, bk1, sf[ni], 0, 0, 0);
        }

        const ushort* bbase = biasb + (size_t)(b * S_ + i0 + wq * 16 + lq * 4) * S_ + j0;
        #pragma unroll
        for (int ni = 0; ni < 4; ni++)
            #pragma unroll
            for (int rr = 0; rr < 4; rr++) {
                float bv = bf2f(bbase[(size_t)rr * S_ + ni * 16 + lc]);
                float p = __builtin_amdgcn_exp2f(fmaf(sf[ni][rr], QSC, bv));
                l_lane[rr] += p;
                Ps[(wq * 16 + lq * 4 + rr) * PSTR + ni * 16 + lc] = f2bf(p);
            }

        bf16x8 ap0 = *(const bf16x8*)&Ps[(wq * 16 + lc) * PSTR + lq * 8];
        bf16x8 ap1 = *(const bf16x8*)&Ps[(wq * 16 + lc) * PSTR + 32 + lq * 8];
        #pragma unroll
        for (int ni = 0; ni < 4; ni++) {
            bf16x8 bv0 = *(const bf16x8*)&Vts[vswz(ni * 16 + lc, lq * 8)];
            bf16x8 bv1 = *(const bf16x8*)&Vts[vswz(ni * 16 + lc, 32 + lq * 8)];
            of[ni] = __builtin_amdgcn_mfma_f32_16x16x32_bf16(ap0, bv0, of[ni], 0, 0, 0);
            of[ni] = __builtin_amdgcn_mfma_f32_16x16x32_bf16(ap1, bv1, of[ni], 0, 0, 0);
        }
    }

    float inv[4];
    #pragma unroll
    for (int rr = 0; rr < 4; rr++) {
        float s = l_lane[rr];
        s += __shfl_xor(s, 1);
        s += __shfl_xor(s, 2);
        s += __shfl_xor(s, 4);
        s += __shfl_xor(s, 8);
        inv[rr] = 1.f / s;
    }
    #pragma unroll
    for (int ni = 0; ni < 4; ni++)
        #pragma unroll
        for (int rr = 0; rr < 4; rr++) {
            int row = i0 + wq * 16 + lq * 4 + rr;
            ao[(size_t)(b * S_ + row) * D_ + h * 64 + ni * 16 + lc] = f2bf(of[ni][rr] * inv[rr]);
        }
}

// ---------------------------------------------------------------------------
// xb = bf16( LayerNorm(xb + pb + bvec) * g + b )  — all-bf16 I/O, fp32 math
// ---------------------------------------------------------------------------
__device__ __forceinline__ float block_sum(float v, float* red) {
    #pragma unroll
    for (int off = 32; off > 0; off >>= 1) v += __shfl_down(v, off);
    int t = threadIdx.x;
    if ((t & 63) == 0) red[t >> 6] = v;
    __syncthreads();
    float r = red[0] + red[1] + red[2] + red[3];
    __syncthreads();
    return r;
}

__global__ __launch_bounds__(256) void add_ln_kernel(
    ushort* __restrict__ xb, const ushort* __restrict__ pb,
    const float* __restrict__ bvec,
    const float* __restrict__ g, const float* __restrict__ bta)
{
    __shared__ float red[4];
    const int row = blockIdx.x;
    const int t = threadIdx.x;
    const size_t base = (size_t)row * D_;
    float v0 = bf2f(xb[base + t])       + bf2f(pb[base + t])       + bvec[t];
    float v1 = bf2f(xb[base + t + 256]) + bf2f(pb[base + t + 256]) + bvec[t + 256];
    float mean = block_sum(v0 + v1, red) * (1.f / (float)D_);
    float d0 = v0 - mean, d1 = v1 - mean;
    float var = block_sum(d0 * d0 + d1 * d1, red) * (1.f / (float)D_);
    float inv = rsqrtf(var + 1e-5f);
    float o0 = d0 * inv * g[t] + bta[t];
    float o1 = d1 * inv * g[t + 256] + bta[t + 256];
    xb[base + t]       = f2bf(o0);
    xb[base + t + 256] = f2bf(o1);
}

// ---------------------------------------------------------------------------
// logits: grid (B, 8); reads bf16 last-row
// ---------------------------------------------------------------------------
__global__ __launch_bounds__(256) void logits_kernel(
    const ushort* __restrict__ xb, const float* __restrict__ lw, float* __restrict__ out)
{
    __shared__ float xs[D_];
    const int b = blockIdx.x;
    const int vchunk = blockIdx.y;
    const int t = threadIdx.x;
    const ushort* xrow = xb + ((size_t)(b * S_ + (S_ - 1)) * D_);
    xs[t] = bf2f(xrow[t]);
    xs[t + 256] = bf2f(xrow[t + 256]);
    __syncthreads();
    for (int vv = vchunk * 128 + t; vv < vchunk * 128 + 128; vv += 256) {
        const float* wr = lw + (size_t)vv * D_;
        float acc = 0.f;
        #pragma unroll 8
        for (int d = 0; d < D_; d += 4) {
            float4 w4 = *(const float4*)&wr[d];
            acc += xs[d] * w4.x + xs[d + 1] * w4.y + xs[d + 2] * w4.z + xs[d + 3] * w4.w;
        }
        out[(size_t)b * VOCAB_ + vv] = acc;
    }
}

// ---------------------------------------------------------------------------
extern "C" void kernel_launch(void* const* d_in, const int* in_sizes, int n_in,
                              void* d_out, int out_size, void* d_ws, size_t ws_size,
                              hipStream_t stream)
{
    const int* raw_x = (const int*)d_in[0];
    const int* sdeg  = (const int*)d_in[1];
    const int* pci   = (const int*)d_in[2];
    const int* pcn   = (const int*)d_in[3];
    const int* sbi   = (const int*)d_in[4];
    const int* sbn   = (const int*)d_in[5];
    const float* vemb = (const float*)d_in[6];
    const float* demb = (const float*)d_in[7];
    const float* arel = (const float*)d_in[8];
    const float* renc = (const float*)d_in[9];
    const float* Wq = (const float*)d_in[10];
    const float* bq = (const float*)d_in[11];
    const float* Wk = (const float*)d_in[12];
    const float* bk = (const float*)d_in[13];
    const float* Wv = (const float*)d_in[14];
    const float* bv = (const float*)d_in[15];
    const float* Wo = (const float*)d_in[16];
    const float* bo = (const float*)d_in[17];
    const float* W1 = (const float*)d_in[18];
    const float* b1 = (const float*)d_in[19];
    const float* W2 = (const float*)d_in[20];
    const float* b2 = (const float*)d_in[21];
    const float* lng = (const float*)d_in[22];
    const float* lnb = (const float*)d_in[23];
    const float* lw  = (const float*)d_in[24];
    float* out = (float*)d_out;

    float* wsf = (float*)d_ws;
    const size_t X = (size_t)BS_ * D_;               // 4,194,304 floats
    ushort* xb   = (ushort*)wsf;                      // [0, 0.5X)
    ushort* qkvb = (ushort*)(wsf + X / 2);            // [0.5X, 2X)   bf16 BS*1536
    ushort* ao   = (ushort*)(wsf + 2 * X);            // [2X, 2.5X)   bf16 BS*512
    ushort* h1   = (ushort*)(wsf + (X * 5) / 2);      // [2.5X, 4.5X) bf16 BS*2048
    ushort* projb= (ushort*)(wsf + (X * 9) / 2);      // [4.5X, 5X)   bf16 BS*512
    float*  bias = wsf + 5 * X;                       // [5X, 6X)     fp32 scatter
    ushort* biasb= (ushort*)(wsf + 6 * X);            // [6X, 6.5X)   bf16 scaled
    ushort* wb   = (ushort*)(wsf + (X * 13) / 2);     // weights bf16: 18,874,368 shorts
    ushort* wqkv_b = wb;                              // L*1536*512
    ushort* wo_b   = wb + 4718592;                    // L*512*512
    ushort* w1_b   = wb + 6291456;                    // L*2048*512
    ushort* w2_b   = wb + 12582912;                   // L*512*2048
    float*  bqkv   = wsf + (X * 13) / 2 + 9437184;    // L*1536 floats

    // --- embeddings (direct to bf16) ---
    embed_kernel<<<(B_ * S_ * D_) / 256, 256, 0, stream>>>(raw_x, sdeg, vemb, demb, xb);
    relnow_kernel<<<B_, D_, 0, stream>>>(pcn, sbn, arel, xb);

    // --- attention bias matrix (fp32 scatter -> bf16 log2e-scaled) ---
    hipMemsetAsync(bias, 0, (size_t)B_ * S_ * S_ * sizeof(float), stream);
    bias_scatter_kernel<<<(NPC_ + NS_ + 255) / 256, 256, 0, stream>>>(pci, sbi, renc, bias);
    bias_cast_kernel<<<(B_ * S_ * S_ / 4) / 256, 256, 0, stream>>>(bias, biasb);

    // --- weight prep ---
    pack_qkv_kernel<<<(L_ * 1536 * 512) / 256, 256, 0, stream>>>(Wq, Wk, Wv, wqkv_b);
    pack_bqkv_kernel<<<(L_ * 1536 + 255) / 256, 256, 0, stream>>>(bq, bk, bv, bqkv);
    cast4_kernel<<<(L_ * 512 * 512) / 4 / 256, 256, 0, stream>>>(Wo, wo_b, L_ * 512 * 512 / 4);
    cast4_kernel<<<(L_ * 2048 * 512) / 4 / 256, 256, 0, stream>>>(W1, w1_b, L_ * 2048 * 512 / 4);
    cast4_kernel<<<(L_ * 512 * 2048) / 4 / 256, 256, 0, stream>>>(W2, w2_b, L_ * 512 * 2048 / 4);

    dim3 blk(256);
    for (int l = 0; l < L_; l++) {
        // QKV: grid x=rows(64), y=cols(12)
        gemm_bf16<<<dim3(BS_ / 128, 1536 / 128), blk, 0, stream>>>(
            xb, wqkv_b + (size_t)l * 1536 * 512, bqkv + l * 1536, qkvb, 512, 1536, 2);

        attn_kernel<<<dim3(S_ / 64, H_, B_), blk, 0, stream>>>(qkvb, biasb, ao);

        // O-proj: grid x=rows(64), y=cols(8), bf16 out
        gemm64<<<dim3(BS_ / 128, 512 / 64), blk, 0, stream>>>(
            ao, wo_b + (size_t)l * 512 * 512, projb, 512, 512);
        add_ln_kernel<<<BS_, blk, 0, stream>>>(xb, projb, bo + l * 512,
                                               lng + l * D_, lnb + l * D_);

        // FFN1: grid x=rows(64), y=cols(16)
        gemm_bf16<<<dim3(BS_ / 128, 2048 / 128), blk, 0, stream>>>(
            xb, w1_b + (size_t)l * 2048 * 512, b1 + l * 2048, h1, 512, 2048, 1);
        // FFN2: grid x=rows(64), y=cols(8), bf16 out
        gemm64<<<dim3(BS_ / 128, 512 / 64), blk, 0, stream>>>(
            h1, w2_b + (size_t)l * 512 * 2048, projb, 2048, 512);
        add_ln_kernel<<<BS_, blk, 0, stream>>>(xb, projb, b2 + l * 512,
                                               lng + l * D_, lnb + l * D_);
    }

    logits_kernel<<<dim3(B_, 8), blk, 0, stream>>>(xb, lw, out);
}

// Round 9
// 1030.366 us; speedup vs baseline: 1.1844x; 1.0503x over previous
//
#include <hip/hip_runtime.h>
#include <hip/hip_bf16.h>
#include <math.h>

#define B_ 16
#define S_ 512
#define D_ 512
#define H_ 8
#define L_ 6
#define DPH_ 64
#define DFF_ 2048
#define VOCAB_ 1024
#define NPC_ 4096
#define NS_ 4096
#define BS_ (B_ * S_)   // 8192 rows
#define LOG2E 1.4426950408889634f

typedef __attribute__((ext_vector_type(8))) short bf16x8;
typedef __attribute__((ext_vector_type(4))) float f32x4;

__device__ __forceinline__ ushort f2bf(float f) {
    __hip_bfloat16 h = __float2bfloat16(f);
    return __builtin_bit_cast(ushort, h);
}
__device__ __forceinline__ float bf2f(ushort u) {
    unsigned int v = ((unsigned int)u) << 16;
    return __builtin_bit_cast(float, v);
}

// ---------------------------------------------------------------------------
// Embedding -> bf16 xb directly
// ---------------------------------------------------------------------------
__global__ __launch_bounds__(256) void embed_kernel(
    const int* __restrict__ raw_x, const int* __restrict__ sdeg,
    const float* __restrict__ vemb, const float* __restrict__ demb,
    ushort* __restrict__ xb)
{
    size_t idx = (size_t)blockIdx.x * 256 + threadIdx.x;
    int d = (int)(idx & (D_ - 1));
    size_t bs = idx >> 9;
    int s = (int)(bs & (S_ - 1));
    int tok = raw_x[bs];
    int dg  = sdeg[bs];
    float e = expf(-(float)(d & ~1) * (9.210340371976184f / (float)D_));
    float ang = (float)s * e;
    float pe = (d & 1) ? cosf(ang) : sinf(ang);
    xb[idx] = f2bf(vemb[(size_t)tok * D_ + d] + pe + demb[(size_t)dg * D_ + d]);
}

__global__ void relnow_kernel(const int* __restrict__ pcn, const int* __restrict__ sbn,
                              const float* __restrict__ arel, ushort* __restrict__ xb)
{
    int b = blockIdx.x;
    int t = threadIdx.x;   // 512 threads
    int b1 = pcn[b * 2 + 0], p1 = pcn[b * 2 + 1];
    size_t i1 = ((size_t)(b1 * S_ + p1)) * D_ + t;
    xb[i1] = f2bf(bf2f(xb[i1]) + arel[t]);
    int b2 = sbn[b * 2 + 0], p2 = sbn[b * 2 + 1];
    size_t i2 = ((size_t)(b2 * S_ + p2)) * D_ + t;
    xb[i2] = f2bf(bf2f(xb[i2]) + arel[D_ + t]);
}

__global__ void bias_scatter_kernel(const int* __restrict__ pc, const int* __restrict__ sb,
                                    const float* __restrict__ renc, float* __restrict__ bias)
{
    int t = blockIdx.x * 256 + threadIdx.x;
    float r0 = renc[0], r1 = renc[1], r2 = renc[2];
    if (t < NPC_) {
        int b = pc[t * 3 + 0], i = pc[t * 3 + 1], j = pc[t * 3 + 2];
        atomicAdd(&bias[((size_t)b * S_ + i) * S_ + j], r0);
        atomicAdd(&bias[((size_t)b * S_ + j) * S_ + i], r1);
    } else if (t < NPC_ + NS_) {
        int u = t - NPC_;
        int b = sb[u * 3 + 0], i = sb[u * 3 + 1], j = sb[u * 3 + 2];
        atomicAdd(&bias[((size_t)b * S_ + i) * S_ + j], r2);
        atomicAdd(&bias[((size_t)b * S_ + j) * S_ + i], r2);
    }
}

__global__ __launch_bounds__(256) void bias_cast_kernel(const float* __restrict__ src,
                                                        ushort* __restrict__ dst)
{
    int i = blockIdx.x * 256 + threadIdx.x;   // < B*S*S/4
    float4 v = ((const float4*)src)[i];
    ushort4 o;
    o.x = f2bf(v.x * LOG2E); o.y = f2bf(v.y * LOG2E);
    o.z = f2bf(v.z * LOG2E); o.w = f2bf(v.w * LOG2E);
    ((ushort4*)dst)[i] = o;
}

// ---------------------------------------------------------------------------
// Weight prep
// ---------------------------------------------------------------------------
__global__ __launch_bounds__(256) void cast4_kernel(const float* __restrict__ src,
                                                    ushort* __restrict__ dst, int n4)
{
    int i = blockIdx.x * 256 + threadIdx.x;
    if (i >= n4) return;
    float4 v = ((const float4*)src)[i];
    ushort4 o;
    o.x = f2bf(v.x); o.y = f2bf(v.y); o.z = f2bf(v.z); o.w = f2bf(v.w);
    ((ushort4*)dst)[i] = o;
}

__global__ __launch_bounds__(256) void pack_qkv_kernel(
    const float* __restrict__ Wq, const float* __restrict__ Wk, const float* __restrict__ Wv,
    ushort* __restrict__ dst)
{
    int idx = blockIdx.x * 256 + threadIdx.x;   // < L*1536*512
    int c = idx & 511;
    int rl = idx >> 9;
    int r = rl % 1536, l = rl / 1536;
    float v;
    if (r < 512)       v = Wq[((size_t)l * 512 + r) * 512 + c];
    else if (r < 1024) v = Wk[((size_t)l * 512 + (r - 512)) * 512 + c];
    else               v = Wv[((size_t)l * 512 + (r - 1024)) * 512 + c];
    dst[idx] = f2bf(v);
}

__global__ void pack_bqkv_kernel(const float* __restrict__ bq, const float* __restrict__ bk,
                                 const float* __restrict__ bv, float* __restrict__ dst)
{
    int idx = blockIdx.x * 256 + threadIdx.x;
    if (idx >= L_ * 1536) return;
    int r = idx % 1536, l = idx / 1536;
    float v;
    if (r < 512)       v = bq[l * 512 + r];
    else if (r < 1024) v = bk[l * 512 + r - 512];
    else               v = bv[l * 512 + r - 1024];
    dst[idx] = v;
}

// ---------------------------------------------------------------------------
// bf16 MFMA NT GEMM, 128x128 tile, PING-PONG pipeline: one barrier per 32-k
// step; stage(next buffer set) issued before compute(current) so the vmcnt
// drain at the next barrier is covered by a full compute phase.
// Grid: x=ROW tile (XCD swizzle), y=COL tile. mode 1: bf16+relu. mode 2: bf16.
// ---------------------------------------------------------------------------
#define GL2LDS(g, l) __builtin_amdgcn_global_load_lds( \
    (const __attribute__((address_space(1))) void*)(g), \
    (__attribute__((address_space(3))) void*)(l), 16, 0, 0)

#define STAGE_AB(AsX, BsX, kk) do {                                            \
    _Pragma("unroll")                                                          \
    for (int i_ = 0; i_ < 2; i_++) {                                           \
        int r_ = i_ * 64 + wv * 16;                                            \
        GL2LDS(A + (size_t)(row0 + r_ + lr) * K + (kk) + lk, &AsX[r_ * 32]);   \
        GL2LDS(W + (size_t)(col0 + r_ + lr) * K + (kk) + lk, &BsX[r_ * 32]);   \
    } } while (0)

#define COMPUTE_AB(AsX, BsX) do {                                              \
    bf16x8 af[4], bf[4];                                                       \
    _Pragma("unroll")                                                          \
    for (int mi = 0; mi < 4; mi++)                                             \
        af[mi] = *(const bf16x8*)&AsX[(wm * 64 + mi * 16 + lc) * 32 + lq * 8]; \
    _Pragma("unroll")                                                          \
    for (int ni = 0; ni < 4; ni++)                                             \
        bf[ni] = *(const bf16x8*)&BsX[(wn * 64 + ni * 16 + lc) * 32 + lq * 8]; \
    _Pragma("unroll")                                                          \
    for (int mi = 0; mi < 4; mi++)                                             \
        _Pragma("unroll")                                                      \
        for (int ni = 0; ni < 4; ni++)                                         \
            acc[mi][ni] = __builtin_amdgcn_mfma_f32_16x16x32_bf16(af[mi], bf[ni], acc[mi][ni], 0, 0, 0); \
    } while (0)

__global__ __launch_bounds__(256) void gemm_bf16(
    const ushort* __restrict__ A, const ushort* __restrict__ W,
    const float* __restrict__ bias, ushort* __restrict__ Cb,
    int K, int M, int mode)
{
    __shared__ ushort As0[128 * 32];
    __shared__ ushort As1[128 * 32];
    __shared__ ushort Bs0[128 * 32];
    __shared__ ushort Bs1[128 * 32];

    const int t  = threadIdx.x;
    const int wv = t >> 6;
    const int ln = t & 63;
    const int wm = wv >> 1, wn = wv & 1;
    const int lq = ln >> 4, lc = ln & 15;
    const int row0 = blockIdx.x * 128;
    const int col0 = blockIdx.y * 128;
    const int lr = ln >> 2;
    const int lk = (ln & 3) * 8;

    f32x4 acc[4][4] = {};
    const int nk = K >> 5;              // 32-k steps (even: 16 or 64)

    STAGE_AB(As0, Bs0, 0);
    for (int ki = 0; ki < nk; ki += 2) {
        __syncthreads();
        if (ki + 1 < nk) STAGE_AB(As1, Bs1, (ki + 1) << 5);
        COMPUTE_AB(As0, Bs0);
        __syncthreads();
        if (ki + 2 < nk) STAGE_AB(As0, Bs0, (ki + 2) << 5);
        COMPUTE_AB(As1, Bs1);
    }

    #pragma unroll
    for (int mi = 0; mi < 4; mi++) {
        #pragma unroll
        for (int ni = 0; ni < 4; ni++) {
            int gcol = col0 + wn * 64 + ni * 16 + lc;
            float bb = bias[gcol];
            #pragma unroll
            for (int rr = 0; rr < 4; rr++) {
                int grow = row0 + wm * 64 + mi * 16 + lq * 4 + rr;
                float val = acc[mi][ni][rr] + bb;
                if (mode == 1) val = fmaxf(val, 0.f);
                Cb[(size_t)grow * M + gcol] = f2bf(val);
            }
        }
    }
}

// ---------------------------------------------------------------------------
// 128-row x 64-col tile, full-K, bf16 out, same ping-pong pipeline.
// Grid: x = ROW tile (64), y = COL tile (8); XCD-swizzled for A-strip reuse.
// ---------------------------------------------------------------------------
#define STAGE_A64(AsX, BsX, kk) do {                                           \
    _Pragma("unroll")                                                          \
    for (int i_ = 0; i_ < 2; i_++) {                                           \
        int r_ = i_ * 64 + wv * 16;                                            \
        GL2LDS(A + (size_t)(row0 + r_ + lr) * K + (kk) + lk, &AsX[r_ * 32]);   \
    }                                                                          \
    {                                                                          \
        int rb_ = wv * 16;                                                     \
        GL2LDS(W + (size_t)(col0 + rb_ + lr) * K + (kk) + lk, &BsX[rb_ * 32]); \
    } } while (0)

#define COMPUTE_A64(AsX, BsX) do {                                             \
    bf16x8 af[4], bf[2];                                                       \
    _Pragma("unroll")                                                          \
    for (int mi = 0; mi < 4; mi++)                                             \
        af[mi] = *(const bf16x8*)&AsX[(wm * 64 + mi * 16 + lc) * 32 + lq * 8]; \
    _Pragma("unroll")                                                          \
    for (int ni = 0; ni < 2; ni++)                                             \
        bf[ni] = *(const bf16x8*)&BsX[(wn * 32 + ni * 16 + lc) * 32 + lq * 8]; \
    _Pragma("unroll")                                                          \
    for (int mi = 0; mi < 4; mi++)                                             \
        _Pragma("unroll")                                                      \
        for (int ni = 0; ni < 2; ni++)                                         \
            acc[mi][ni] = __builtin_amdgcn_mfma_f32_16x16x32_bf16(af[mi], bf[ni], acc[mi][ni], 0, 0, 0); \
    } while (0)

__global__ __launch_bounds__(256) void gemm64(
    const ushort* __restrict__ A, const ushort* __restrict__ W,
    ushort* __restrict__ Cb, int K, int M)
{
    __shared__ ushort As0[128 * 32];
    __shared__ ushort As1[128 * 32];
    __shared__ ushort Bs0[64 * 32];
    __shared__ ushort Bs1[64 * 32];

    const int t  = threadIdx.x;
    const int wv = t >> 6;
    const int ln = t & 63;
    const int wm = wv >> 1, wn = wv & 1;
    const int lq = ln >> 4, lc = ln & 15;
    const int row0 = blockIdx.x * 128;
    const int col0 = blockIdx.y * 64;
    const int lr = ln >> 2;
    const int lk = (ln & 3) * 8;

    f32x4 acc[4][2] = {};
    const int nk = K >> 5;

    STAGE_A64(As0, Bs0, 0);
    for (int ki = 0; ki < nk; ki += 2) {
        __syncthreads();
        if (ki + 1 < nk) STAGE_A64(As1, Bs1, (ki + 1) << 5);
        COMPUTE_A64(As0, Bs0);
        __syncthreads();
        if (ki + 2 < nk) STAGE_A64(As0, Bs0, (ki + 2) << 5);
        COMPUTE_A64(As1, Bs1);
    }

    #pragma unroll
    for (int mi = 0; mi < 4; mi++)
        #pragma unroll
        for (int ni = 0; ni < 2; ni++) {
            int gcol = col0 + wn * 32 + ni * 16 + lc;
            #pragma unroll
            for (int rr = 0; rr < 4; rr++) {
                int grow = row0 + wm * 64 + mi * 16 + lq * 4 + rr;
                Cb[(size_t)grow * M + gcol] = f2bf(acc[mi][ni][rr]);
            }
        }
}

// ---------------------------------------------------------------------------
// MFMA flash attention, no-max softmax. j-UNROLLED x2: stage 128 keys/values
// per barrier pair (8 barriers/block instead of 16).
// ---------------------------------------------------------------------------
#define PSTR 72

__device__ __forceinline__ int vswz(int d, int j) {
    int g = ((j >> 3) ^ (d & 7) ^ ((d >> 3) & 7)) & 7;
    return d * 64 + g * 8 + (j & 7);
}

// One 64-key sub-tile: S = Q*K^T, p = exp2(s*qsc + bias), O += P*V
#define ATTN_SUB(KsX, VtsX, jbase) do {                                        \
    f32x4 sf[4] = {};                                                          \
    _Pragma("unroll")                                                          \
    for (int ni = 0; ni < 4; ni++) {                                           \
        bf16x8 bk0 = *(const bf16x8*)&KsX[(ni * 16 + lc) * PSTR + lq * 8];     \
        bf16x8 bk1 = *(const bf16x8*)&KsX[(ni * 16 + lc) * PSTR + 32 + lq * 8];\
        sf[ni] = __builtin_amdgcn_mfma_f32_16x16x32_bf16(aq0, bk0, sf[ni], 0, 0, 0); \
        sf[ni] = __builtin_amdgcn_mfma_f32_16x16x32_bf16(aq1, bk1, sf[ni], 0, 0, 0); \
    }                                                                          \
    const ushort* bbase = biasb + (size_t)(b * S_ + i0 + wq * 16 + lq * 4) * S_ + (jbase); \
    _Pragma("unroll")                                                          \
    for (int ni = 0; ni < 4; ni++)                                             \
        _Pragma("unroll")                                                      \
        for (int rr = 0; rr < 4; rr++) {                                       \
            float bv = bf2f(bbase[(size_t)rr * S_ + ni * 16 + lc]);            \
            float p = __builtin_amdgcn_exp2f(fmaf(sf[ni][rr], QSC, bv));       \
            l_lane[rr] += p;                                                   \
            Ps[(wq * 16 + lq * 4 + rr) * PSTR + ni * 16 + lc] = f2bf(p);       \
        }                                                                      \
    bf16x8 ap0 = *(const bf16x8*)&Ps[(wq * 16 + lc) * PSTR + lq * 8];          \
    bf16x8 ap1 = *(const bf16x8*)&Ps[(wq * 16 + lc) * PSTR + 32 + lq * 8];     \
    _Pragma("unroll")                                                          \
    for (int ni = 0; ni < 4; ni++) {                                           \
        bf16x8 bv0 = *(const bf16x8*)&VtsX[vswz(ni * 16 + lc, lq * 8)];        \
        bf16x8 bv1 = *(const bf16x8*)&VtsX[vswz(ni * 16 + lc, 32 + lq * 8)];   \
        of[ni] = __builtin_amdgcn_mfma_f32_16x16x32_bf16(ap0, bv0, of[ni], 0, 0, 0); \
        of[ni] = __builtin_amdgcn_mfma_f32_16x16x32_bf16(ap1, bv1, of[ni], 0, 0, 0); \
    } } while (0)

__global__ __launch_bounds__(256) void attn_kernel(
    const ushort* __restrict__ qkv, const ushort* __restrict__ biasb,
    ushort* __restrict__ ao)
{
    const int qt = blockIdx.x, h = blockIdx.y, b = blockIdx.z;
    const int t  = threadIdx.x;
    const int wq = t >> 6;
    const int ln = t & 63;
    const int lq = ln >> 4;
    const int lc = ln & 15;
    const int r  = t >> 2;
    const int cg = t & 3;

    __shared__ ushort Qs[64 * PSTR];
    __shared__ ushort Ks0[64 * PSTR];
    __shared__ ushort Ks1[64 * PSTR];
    __shared__ ushort Ps[64 * PSTR];
    __shared__ ushort Vts0[64 * 64];
    __shared__ ushort Vts1[64 * 64];

    const int i0 = qt * 64;

    // stage Q (each wave stages exactly its own 16 rows -> wave-local)
    {
        const ushort* qsrc = qkv + (size_t)(b * S_ + i0 + r) * 1536 + h * 64 + cg * 16;
        *(uint4*)&Qs[r * PSTR + cg * 16]     = ((const uint4*)qsrc)[0];
        *(uint4*)&Qs[r * PSTR + cg * 16 + 8] = ((const uint4*)qsrc)[1];
    }
    bf16x8 aq0 = *(const bf16x8*)&Qs[(wq * 16 + lc) * PSTR + lq * 8];
    bf16x8 aq1 = *(const bf16x8*)&Qs[(wq * 16 + lc) * PSTR + 32 + lq * 8];

    f32x4 of[4] = {};
    float l_lane[4] = {};
    const float QSC = 0.125f * LOG2E;

    for (int j0 = 0; j0 < S_; j0 += 128) {
        __syncthreads();   // previous iter's K/Vt consumers done
        {
            const ushort* ksrc0 = qkv + (size_t)(b * S_ + j0 + r) * 1536 + 512 + h * 64 + cg * 16;
            const ushort* ksrc1 = ksrc0 + (size_t)64 * 1536;
            *(uint4*)&Ks0[r * PSTR + cg * 16]     = ((const uint4*)ksrc0)[0];
            *(uint4*)&Ks0[r * PSTR + cg * 16 + 8] = ((const uint4*)ksrc0)[1];
            *(uint4*)&Ks1[r * PSTR + cg * 16]     = ((const uint4*)ksrc1)[0];
            *(uint4*)&Ks1[r * PSTR + cg * 16 + 8] = ((const uint4*)ksrc1)[1];
            ushort vv[16];
            *(uint4*)&vv[0] = ((const uint4*)(ksrc0 + 512))[0];
            *(uint4*)&vv[8] = ((const uint4*)(ksrc0 + 512))[1];
            #pragma unroll
            for (int dd = 0; dd < 16; dd++)
                Vts0[vswz(cg * 16 + dd, r)] = vv[dd];
            *(uint4*)&vv[0] = ((const uint4*)(ksrc1 + 512))[0];
            *(uint4*)&vv[8] = ((const uint4*)(ksrc1 + 512))[1];
            #pragma unroll
            for (int dd = 0; dd < 16; dd++)
                Vts1[vswz(cg * 16 + dd, r)] = vv[dd];
        }
        __syncthreads();

        ATTN_SUB(Ks0, Vts0, j0);
        ATTN_SUB(Ks1, Vts1, j0 + 64);
    }

    float inv[4];
    #pragma unroll
    for (int rr = 0; rr < 4; rr++) {
        float s = l_lane[rr];
        s += __shfl_xor(s, 1);
        s += __shfl_xor(s, 2);
        s += __shfl_xor(s, 4);
        s += __shfl_xor(s, 8);
        inv[rr] = 1.f / s;
    }
    #pragma unroll
    for (int ni = 0; ni < 4; ni++)
        #pragma unroll
        for (int rr = 0; rr < 4; rr++) {
            int row = i0 + wq * 16 + lq * 4 + rr;
            ao[(size_t)(b * S_ + row) * D_ + h * 64 + ni * 16 + lc] = f2bf(of[ni][rr] * inv[rr]);
        }
}

// ---------------------------------------------------------------------------
// xb = bf16( LayerNorm(xb + pb + bvec) * g + b )
// ---------------------------------------------------------------------------
__device__ __forceinline__ float block_sum(float v, float* red) {
    #pragma unroll
    for (int off = 32; off > 0; off >>= 1) v += __shfl_down(v, off);
    int t = threadIdx.x;
    if ((t & 63) == 0) red[t >> 6] = v;
    __syncthreads();
    float r = red[0] + red[1] + red[2] + red[3];
    __syncthreads();
    return r;
}

__global__ __launch_bounds__(256) void add_ln_kernel(
    ushort* __restrict__ xb, const ushort* __restrict__ pb,
    const float* __restrict__ bvec,
    const float* __restrict__ g, const float* __restrict__ bta)
{
    __shared__ float red[4];
    const int row = blockIdx.x;
    const int t = threadIdx.x;
    const size_t base = (size_t)row * D_;
    float v0 = bf2f(xb[base + t])       + bf2f(pb[base + t])       + bvec[t];
    float v1 = bf2f(xb[base + t + 256]) + bf2f(pb[base + t + 256]) + bvec[t + 256];
    float mean = block_sum(v0 + v1, red) * (1.f / (float)D_);
    float d0 = v0 - mean, d1 = v1 - mean;
    float var = block_sum(d0 * d0 + d1 * d1, red) * (1.f / (float)D_);
    float inv = rsqrtf(var + 1e-5f);
    float o0 = d0 * inv * g[t] + bta[t];
    float o1 = d1 * inv * g[t + 256] + bta[t + 256];
    xb[base + t]       = f2bf(o0);
    xb[base + t + 256] = f2bf(o1);
}

// ---------------------------------------------------------------------------
// logits: grid (B, 8); reads bf16 last-row
// ---------------------------------------------------------------------------
__global__ __launch_bounds__(256) void logits_kernel(
    const ushort* __restrict__ xb, const float* __restrict__ lw, float* __restrict__ out)
{
    __shared__ float xs[D_];
    const int b = blockIdx.x;
    const int vchunk = blockIdx.y;
    const int t = threadIdx.x;
    const ushort* xrow = xb + ((size_t)(b * S_ + (S_ - 1)) * D_);
    xs[t] = bf2f(xrow[t]);
    xs[t + 256] = bf2f(xrow[t + 256]);
    __syncthreads();
    for (int vv = vchunk * 128 + t; vv < vchunk * 128 + 128; vv += 256) {
        const float* wr = lw + (size_t)vv * D_;
        float acc = 0.f;
        #pragma unroll 8
        for (int d = 0; d < D_; d += 4) {
            float4 w4 = *(const float4*)&wr[d];
            acc += xs[d] * w4.x + xs[d + 1] * w4.y + xs[d + 2] * w4.z + xs[d + 3] * w4.w;
        }
        out[(size_t)b * VOCAB_ + vv] = acc;
    }
}

// ---------------------------------------------------------------------------
extern "C" void kernel_launch(void* const* d_in, const int* in_sizes, int n_in,
                              void* d_out, int out_size, void* d_ws, size_t ws_size,
                              hipStream_t stream)
{
    const int* raw_x = (const int*)d_in[0];
    const int* sdeg  = (const int*)d_in[1];
    const int* pci   = (const int*)d_in[2];
    const int* pcn   = (const int*)d_in[3];
    const int* sbi   = (const int*)d_in[4];
    const int* sbn   = (const int*)d_in[5];
    const float* vemb = (const float*)d_in[6];
    const float* demb = (const float*)d_in[7];
    const float* arel = (const float*)d_in[8];
    const float* renc = (const float*)d_in[9];
    const float* Wq = (const float*)d_in[10];
    const float* bq = (const float*)d_in[11];
    const float* Wk = (const float*)d_in[12];
    const float* bk = (const float*)d_in[13];
    const float* Wv = (const float*)d_in[14];
    const float* bv = (const float*)d_in[15];
    const float* Wo = (const float*)d_in[16];
    const float* bo = (const float*)d_in[17];
    const float* W1 = (const float*)d_in[18];
    const float* b1 = (const float*)d_in[19];
    const float* W2 = (const float*)d_in[20];
    const float* b2 = (const float*)d_in[21];
    const float* lng = (const float*)d_in[22];
    const float* lnb = (const float*)d_in[23];
    const float* lw  = (const float*)d_in[24];
    float* out = (float*)d_out;

    float* wsf = (float*)d_ws;
    const size_t X = (size_t)BS_ * D_;               // 4,194,304 floats
    ushort* xb   = (ushort*)wsf;                      // [0, 0.5X)
    ushort* qkvb = (ushort*)(wsf + X / 2);            // [0.5X, 2X)   bf16 BS*1536
    ushort* ao   = (ushort*)(wsf + 2 * X);            // [2X, 2.5X)   bf16 BS*512
    ushort* h1   = (ushort*)(wsf + (X * 5) / 2);      // [2.5X, 4.5X) bf16 BS*2048
    ushort* projb= (ushort*)(wsf + (X * 9) / 2);      // [4.5X, 5X)   bf16 BS*512
    float*  bias = wsf + 5 * X;                       // [5X, 6X)     fp32 scatter
    ushort* biasb= (ushort*)(wsf + 6 * X);            // [6X, 6.5X)   bf16 scaled
    ushort* wb   = (ushort*)(wsf + (X * 13) / 2);     // weights bf16: 18,874,368 shorts
    ushort* wqkv_b = wb;                              // L*1536*512
    ushort* wo_b   = wb + 4718592;                    // L*512*512
    ushort* w1_b   = wb + 6291456;                    // L*2048*512
    ushort* w2_b   = wb + 12582912;                   // L*512*2048
    float*  bqkv   = wsf + (X * 13) / 2 + 9437184;    // L*1536 floats

    // --- embeddings (direct to bf16) ---
    embed_kernel<<<(B_ * S_ * D_) / 256, 256, 0, stream>>>(raw_x, sdeg, vemb, demb, xb);
    relnow_kernel<<<B_, D_, 0, stream>>>(pcn, sbn, arel, xb);

    // --- attention bias matrix (fp32 scatter -> bf16 log2e-scaled) ---
    hipMemsetAsync(bias, 0, (size_t)B_ * S_ * S_ * sizeof(float), stream);
    bias_scatter_kernel<<<(NPC_ + NS_ + 255) / 256, 256, 0, stream>>>(pci, sbi, renc, bias);
    bias_cast_kernel<<<(B_ * S_ * S_ / 4) / 256, 256, 0, stream>>>(bias, biasb);

    // --- weight prep ---
    pack_qkv_kernel<<<(L_ * 1536 * 512) / 256, 256, 0, stream>>>(Wq, Wk, Wv, wqkv_b);
    pack_bqkv_kernel<<<(L_ * 1536 + 255) / 256, 256, 0, stream>>>(bq, bk, bv, bqkv);
    cast4_kernel<<<(L_ * 512 * 512) / 4 / 256, 256, 0, stream>>>(Wo, wo_b, L_ * 512 * 512 / 4);
    cast4_kernel<<<(L_ * 2048 * 512) / 4 / 256, 256, 0, stream>>>(W1, w1_b, L_ * 2048 * 512 / 4);
    cast4_kernel<<<(L_ * 512 * 2048) / 4 / 256, 256, 0, stream>>>(W2, w2_b, L_ * 512 * 2048 / 4);

    dim3 blk(256);
    for (int l = 0; l < L_; l++) {
        // QKV: grid x=rows(64), y=cols(12)
        gemm_bf16<<<dim3(BS_ / 128, 1536 / 128), blk, 0, stream>>>(
            xb, wqkv_b + (size_t)l * 1536 * 512, bqkv + l * 1536, qkvb, 512, 1536, 2);

        attn_kernel<<<dim3(S_ / 64, H_, B_), blk, 0, stream>>>(qkvb, biasb, ao);

        // O-proj: grid x=rows(64), y=cols(8), bf16 out
        gemm64<<<dim3(BS_ / 128, 512 / 64), blk, 0, stream>>>(
            ao, wo_b + (size_t)l * 512 * 512, projb, 512, 512);
        add_ln_kernel<<<BS_, blk, 0, stream>>>(xb, projb, bo + l * 512,
                                               lng + l * D_, lnb + l * D_);

        // FFN1: grid x=rows(64), y=cols(16)
        gemm_bf16<<<dim3(BS_ / 128, 2048 / 128), blk, 0, stream>>>(
            xb, w1_b + (size_t)l * 2048 * 512, b1 + l * 2048, h1, 512, 2048, 1);
        // FFN2: grid x=rows(64), y=cols(8), bf16 out
        gemm64<<<dim3(BS_ / 128, 512 / 64), blk, 0, stream>>>(
            h1, w2_b + (size_t)l * 512 * 2048, projb, 2048, 512);
        add_ln_kernel<<<BS_, blk, 0, stream>>>(xb, projb, b2 + l * 512,
                                               lng + l * D_, lnb + l * D_);
    }

    logits_kernel<<<dim3(B_, 8), blk, 0, stream>>>(xb, lw, out);
}

// Round 10
// 950.115 us; speedup vs baseline: 1.2845x; 1.0845x over previous
//
#include <hip/hip_runtime.h>
#include <hip/hip_bf16.h>
#include <math.h>

#define B_ 16
#define S_ 512
#define D_ 512
#define H_ 8
#define L_ 6
#define DPH_ 64
#define DFF_ 2048
#define VOCAB_ 1024
#define NPC_ 4096
#define NS_ 4096
#define BS_ (B_ * S_)   // 8192 rows
#define LOG2E 1.4426950408889634f

typedef __attribute__((ext_vector_type(8))) short bf16x8;
typedef __attribute__((ext_vector_type(4))) float f32x4;

__device__ __forceinline__ ushort f2bf(float f) {
    __hip_bfloat16 h = __float2bfloat16(f);
    return __builtin_bit_cast(ushort, h);
}
__device__ __forceinline__ float bf2f(ushort u) {
    unsigned int v = ((unsigned int)u) << 16;
    return __builtin_bit_cast(float, v);
}

// ---------------------------------------------------------------------------
// Embedding -> bf16 xb directly
// ---------------------------------------------------------------------------
__global__ __launch_bounds__(256) void embed_kernel(
    const int* __restrict__ raw_x, const int* __restrict__ sdeg,
    const float* __restrict__ vemb, const float* __restrict__ demb,
    ushort* __restrict__ xb)
{
    size_t idx = (size_t)blockIdx.x * 256 + threadIdx.x;
    int d = (int)(idx & (D_ - 1));
    size_t bs = idx >> 9;
    int s = (int)(bs & (S_ - 1));
    int tok = raw_x[bs];
    int dg  = sdeg[bs];
    float e = expf(-(float)(d & ~1) * (9.210340371976184f / (float)D_));
    float ang = (float)s * e;
    float pe = (d & 1) ? cosf(ang) : sinf(ang);
    xb[idx] = f2bf(vemb[(size_t)tok * D_ + d] + pe + demb[(size_t)dg * D_ + d]);
}

__global__ void relnow_kernel(const int* __restrict__ pcn, const int* __restrict__ sbn,
                              const float* __restrict__ arel, ushort* __restrict__ xb)
{
    int b = blockIdx.x;
    int t = threadIdx.x;   // 512 threads
    int b1 = pcn[b * 2 + 0], p1 = pcn[b * 2 + 1];
    size_t i1 = ((size_t)(b1 * S_ + p1)) * D_ + t;
    xb[i1] = f2bf(bf2f(xb[i1]) + arel[t]);
    int b2 = sbn[b * 2 + 0], p2 = sbn[b * 2 + 1];
    size_t i2 = ((size_t)(b2 * S_ + p2)) * D_ + t;
    xb[i2] = f2bf(bf2f(xb[i2]) + arel[D_ + t]);
}

__global__ void bias_scatter_kernel(const int* __restrict__ pc, const int* __restrict__ sb,
                                    const float* __restrict__ renc, float* __restrict__ bias)
{
    int t = blockIdx.x * 256 + threadIdx.x;
    float r0 = renc[0], r1 = renc[1], r2 = renc[2];
    if (t < NPC_) {
        int b = pc[t * 3 + 0], i = pc[t * 3 + 1], j = pc[t * 3 + 2];
        atomicAdd(&bias[((size_t)b * S_ + i) * S_ + j], r0);
        atomicAdd(&bias[((size_t)b * S_ + j) * S_ + i], r1);
    } else if (t < NPC_ + NS_) {
        int u = t - NPC_;
        int b = sb[u * 3 + 0], i = sb[u * 3 + 1], j = sb[u * 3 + 2];
        atomicAdd(&bias[((size_t)b * S_ + i) * S_ + j], r2);
        atomicAdd(&bias[((size_t)b * S_ + j) * S_ + i], r2);
    }
}

__global__ __launch_bounds__(256) void bias_cast_kernel(const float* __restrict__ src,
                                                        ushort* __restrict__ dst)
{
    int i = blockIdx.x * 256 + threadIdx.x;   // < B*S*S/4
    float4 v = ((const float4*)src)[i];
    ushort4 o;
    o.x = f2bf(v.x * LOG2E); o.y = f2bf(v.y * LOG2E);
    o.z = f2bf(v.z * LOG2E); o.w = f2bf(v.w * LOG2E);
    ((ushort4*)dst)[i] = o;
}

// ---------------------------------------------------------------------------
// Weight prep
// ---------------------------------------------------------------------------
__global__ __launch_bounds__(256) void cast4_kernel(const float* __restrict__ src,
                                                    ushort* __restrict__ dst, int n4)
{
    int i = blockIdx.x * 256 + threadIdx.x;
    if (i >= n4) return;
    float4 v = ((const float4*)src)[i];
    ushort4 o;
    o.x = f2bf(v.x); o.y = f2bf(v.y); o.z = f2bf(v.z); o.w = f2bf(v.w);
    ((ushort4*)dst)[i] = o;
}

__global__ __launch_bounds__(256) void pack_qkv_kernel(
    const float* __restrict__ Wq, const float* __restrict__ Wk, const float* __restrict__ Wv,
    ushort* __restrict__ dst)
{
    int idx = blockIdx.x * 256 + threadIdx.x;   // < L*1536*512
    int c = idx & 511;
    int rl = idx >> 9;
    int r = rl % 1536, l = rl / 1536;
    float v;
    if (r < 512)       v = Wq[((size_t)l * 512 + r) * 512 + c];
    else if (r < 1024) v = Wk[((size_t)l * 512 + (r - 512)) * 512 + c];
    else               v = Wv[((size_t)l * 512 + (r - 1024)) * 512 + c];
    dst[idx] = f2bf(v);
}

__global__ void pack_bqkv_kernel(const float* __restrict__ bq, const float* __restrict__ bk,
                                 const float* __restrict__ bv, float* __restrict__ dst)
{
    int idx = blockIdx.x * 256 + threadIdx.x;
    if (idx >= L_ * 1536) return;
    int r = idx % 1536, l = idx / 1536;
    float v;
    if (r < 512)       v = bq[l * 512 + r];
    else if (r < 1024) v = bk[l * 512 + r - 512];
    else               v = bv[l * 512 + r - 1024];
    dst[idx] = v;
}

// ---------------------------------------------------------------------------
// bf16 MFMA NT GEMM, 128x128 tile, ping-pong pipeline (one barrier / 32-k).
// Grid: x=ROW tile (XCD swizzle), y=COL tile. mode 1: bf16+relu. mode 2: bf16.
// ---------------------------------------------------------------------------
#define GL2LDS(g, l) __builtin_amdgcn_global_load_lds( \
    (const __attribute__((address_space(1))) void*)(g), \
    (__attribute__((address_space(3))) void*)(l), 16, 0, 0)

#define STAGE_AB(AsX, BsX, kk) do {                                            \
    _Pragma("unroll")                                                          \
    for (int i_ = 0; i_ < 2; i_++) {                                           \
        int r_ = i_ * 64 + wv * 16;                                            \
        GL2LDS(A + (size_t)(row0 + r_ + lr) * K + (kk) + lk, &AsX[r_ * 32]);   \
        GL2LDS(W + (size_t)(col0 + r_ + lr) * K + (kk) + lk, &BsX[r_ * 32]);   \
    } } while (0)

#define COMPUTE_AB(AsX, BsX) do {                                              \
    bf16x8 af[4], bf[4];                                                       \
    _Pragma("unroll")                                                          \
    for (int mi = 0; mi < 4; mi++)                                             \
        af[mi] = *(const bf16x8*)&AsX[(wm * 64 + mi * 16 + lc) * 32 + lq * 8]; \
    _Pragma("unroll")                                                          \
    for (int ni = 0; ni < 4; ni++)                                             \
        bf[ni] = *(const bf16x8*)&BsX[(wn * 64 + ni * 16 + lc) * 32 + lq * 8]; \
    _Pragma("unroll")                                                          \
    for (int mi = 0; mi < 4; mi++)                                             \
        _Pragma("unroll")                                                      \
        for (int ni = 0; ni < 4; ni++)                                         \
            acc[mi][ni] = __builtin_amdgcn_mfma_f32_16x16x32_bf16(af[mi], bf[ni], acc[mi][ni], 0, 0, 0); \
    } while (0)

__global__ __launch_bounds__(256) void gemm_bf16(
    const ushort* __restrict__ A, const ushort* __restrict__ W,
    const float* __restrict__ bias, ushort* __restrict__ Cb,
    int K, int M, int mode)
{
    __shared__ ushort As0[128 * 32];
    __shared__ ushort As1[128 * 32];
    __shared__ ushort Bs0[128 * 32];
    __shared__ ushort Bs1[128 * 32];

    const int t  = threadIdx.x;
    const int wv = t >> 6;
    const int ln = t & 63;
    const int wm = wv >> 1, wn = wv & 1;
    const int lq = ln >> 4, lc = ln & 15;
    const int row0 = blockIdx.x * 128;
    const int col0 = blockIdx.y * 128;
    const int lr = ln >> 2;
    const int lk = (ln & 3) * 8;

    f32x4 acc[4][4] = {};
    const int nk = K >> 5;              // 32-k steps

    STAGE_AB(As0, Bs0, 0);
    for (int ki = 0; ki < nk; ki += 2) {
        __syncthreads();
        if (ki + 1 < nk) STAGE_AB(As1, Bs1, (ki + 1) << 5);
        COMPUTE_AB(As0, Bs0);
        __syncthreads();
        if (ki + 2 < nk) STAGE_AB(As0, Bs0, (ki + 2) << 5);
        COMPUTE_AB(As1, Bs1);
    }

    #pragma unroll
    for (int mi = 0; mi < 4; mi++) {
        #pragma unroll
        for (int ni = 0; ni < 4; ni++) {
            int gcol = col0 + wn * 64 + ni * 16 + lc;
            float bb = bias[gcol];
            #pragma unroll
            for (int rr = 0; rr < 4; rr++) {
                int grow = row0 + wm * 64 + mi * 16 + lq * 4 + rr;
                float val = acc[mi][ni][rr] + bb;
                if (mode == 1) val = fmaxf(val, 0.f);
                Cb[(size_t)grow * M + gcol] = f2bf(val);
            }
        }
    }
}

// ---------------------------------------------------------------------------
// 128-row x 64-col tile, full-K, bf16 out, ping-pong. Grid x=ROW, y=COL.
// ---------------------------------------------------------------------------
#define STAGE_A64(AsX, BsX, kk) do {                                           \
    _Pragma("unroll")                                                          \
    for (int i_ = 0; i_ < 2; i_++) {                                           \
        int r_ = i_ * 64 + wv * 16;                                            \
        GL2LDS(A + (size_t)(row0 + r_ + lr) * K + (kk) + lk, &AsX[r_ * 32]);   \
    }                                                                          \
    {                                                                          \
        int rb_ = wv * 16;                                                     \
        GL2LDS(W + (size_t)(col0 + rb_ + lr) * K + (kk) + lk, &BsX[rb_ * 32]); \
    } } while (0)

#define COMPUTE_A64(AsX, BsX) do {                                             \
    bf16x8 af[4], bf[2];                                                       \
    _Pragma("unroll")                                                          \
    for (int mi = 0; mi < 4; mi++)                                             \
        af[mi] = *(const bf16x8*)&AsX[(wm * 64 + mi * 16 + lc) * 32 + lq * 8]; \
    _Pragma("unroll")                                                          \
    for (int ni = 0; ni < 2; ni++)                                             \
        bf[ni] = *(const bf16x8*)&BsX[(wn * 32 + ni * 16 + lc) * 32 + lq * 8]; \
    _Pragma("unroll")                                                          \
    for (int mi = 0; mi < 4; mi++)                                             \
        _Pragma("unroll")                                                      \
        for (int ni = 0; ni < 2; ni++)                                         \
            acc[mi][ni] = __builtin_amdgcn_mfma_f32_16x16x32_bf16(af[mi], bf[ni], acc[mi][ni], 0, 0, 0); \
    } while (0)

__global__ __launch_bounds__(256) void gemm64(
    const ushort* __restrict__ A, const ushort* __restrict__ W,
    ushort* __restrict__ Cb, int K, int M)
{
    __shared__ ushort As0[128 * 32];
    __shared__ ushort As1[128 * 32];
    __shared__ ushort Bs0[64 * 32];
    __shared__ ushort Bs1[64 * 32];

    const int t  = threadIdx.x;
    const int wv = t >> 6;
    const int ln = t & 63;
    const int wm = wv >> 1, wn = wv & 1;
    const int lq = ln >> 4, lc = ln & 15;
    const int row0 = blockIdx.x * 128;
    const int col0 = blockIdx.y * 64;
    const int lr = ln >> 2;
    const int lk = (ln & 3) * 8;

    f32x4 acc[4][2] = {};
    const int nk = K >> 5;

    STAGE_A64(As0, Bs0, 0);
    for (int ki = 0; ki < nk; ki += 2) {
        __syncthreads();
        if (ki + 1 < nk) STAGE_A64(As1, Bs1, (ki + 1) << 5);
        COMPUTE_A64(As0, Bs0);
        __syncthreads();
        if (ki + 2 < nk) STAGE_A64(As0, Bs0, (ki + 2) << 5);
        COMPUTE_A64(As1, Bs1);
    }

    #pragma unroll
    for (int mi = 0; mi < 4; mi++)
        #pragma unroll
        for (int ni = 0; ni < 2; ni++) {
            int gcol = col0 + wn * 32 + ni * 16 + lc;
            #pragma unroll
            for (int rr = 0; rr < 4; rr++) {
                int grow = row0 + wm * 64 + mi * 16 + lq * 4 + rr;
                Cb[(size_t)grow * M + gcol] = f2bf(acc[mi][ni][rr]);
            }
        }
}

// ---------------------------------------------------------------------------
// MFMA flash attention, no-max softmax, j-unrolled x2 (layers 0..4)
// ---------------------------------------------------------------------------
#define PSTR 72

__device__ __forceinline__ int vswz(int d, int j) {
    int g = ((j >> 3) ^ (d & 7) ^ ((d >> 3) & 7)) & 7;
    return d * 64 + g * 8 + (j & 7);
}

#define ATTN_SUB(KsX, VtsX, jbase) do {                                        \
    f32x4 sf[4] = {};                                                          \
    _Pragma("unroll")                                                          \
    for (int ni = 0; ni < 4; ni++) {                                           \
        bf16x8 bk0 = *(const bf16x8*)&KsX[(ni * 16 + lc) * PSTR + lq * 8];     \
        bf16x8 bk1 = *(const bf16x8*)&KsX[(ni * 16 + lc) * PSTR + 32 + lq * 8];\
        sf[ni] = __builtin_amdgcn_mfma_f32_16x16x32_bf16(aq0, bk0, sf[ni], 0, 0, 0); \
        sf[ni] = __builtin_amdgcn_mfma_f32_16x16x32_bf16(aq1, bk1, sf[ni], 0, 0, 0); \
    }                                                                          \
    const ushort* bbase = biasb + (size_t)(b * S_ + i0 + wq * 16 + lq * 4) * S_ + (jbase); \
    _Pragma("unroll")                                                          \
    for (int ni = 0; ni < 4; ni++)                                             \
        _Pragma("unroll")                                                      \
        for (int rr = 0; rr < 4; rr++) {                                       \
            float bv = bf2f(bbase[(size_t)rr * S_ + ni * 16 + lc]);            \
            float p = __builtin_amdgcn_exp2f(fmaf(sf[ni][rr], QSC, bv));       \
            l_lane[rr] += p;                                                   \
            Ps[(wq * 16 + lq * 4 + rr) * PSTR + ni * 16 + lc] = f2bf(p);       \
        }                                                                      \
    bf16x8 ap0 = *(const bf16x8*)&Ps[(wq * 16 + lc) * PSTR + lq * 8];          \
    bf16x8 ap1 = *(const bf16x8*)&Ps[(wq * 16 + lc) * PSTR + 32 + lq * 8];     \
    _Pragma("unroll")                                                          \
    for (int ni = 0; ni < 4; ni++) {                                           \
        bf16x8 bv0 = *(const bf16x8*)&VtsX[vswz(ni * 16 + lc, lq * 8)];        \
        bf16x8 bv1 = *(const bf16x8*)&VtsX[vswz(ni * 16 + lc, 32 + lq * 8)];   \
        of[ni] = __builtin_amdgcn_mfma_f32_16x16x32_bf16(ap0, bv0, of[ni], 0, 0, 0); \
        of[ni] = __builtin_amdgcn_mfma_f32_16x16x32_bf16(ap1, bv1, of[ni], 0, 0, 0); \
    } } while (0)

__global__ __launch_bounds__(256) void attn_kernel(
    const ushort* __restrict__ qkv, const ushort* __restrict__ biasb,
    ushort* __restrict__ ao)
{
    const int qt = blockIdx.x, h = blockIdx.y, b = blockIdx.z;
    const int t  = threadIdx.x;
    const int wq = t >> 6;
    const int ln = t & 63;
    const int lq = ln >> 4;
    const int lc = ln & 15;
    const int r  = t >> 2;
    const int cg = t & 3;

    __shared__ ushort Qs[64 * PSTR];
    __shared__ ushort Ks0[64 * PSTR];
    __shared__ ushort Ks1[64 * PSTR];
    __shared__ ushort Ps[64 * PSTR];
    __shared__ ushort Vts0[64 * 64];
    __shared__ ushort Vts1[64 * 64];

    const int i0 = qt * 64;

    {
        const ushort* qsrc = qkv + (size_t)(b * S_ + i0 + r) * 1536 + h * 64 + cg * 16;
        *(uint4*)&Qs[r * PSTR + cg * 16]     = ((const uint4*)qsrc)[0];
        *(uint4*)&Qs[r * PSTR + cg * 16 + 8] = ((const uint4*)qsrc)[1];
    }
    bf16x8 aq0 = *(const bf16x8*)&Qs[(wq * 16 + lc) * PSTR + lq * 8];
    bf16x8 aq1 = *(const bf16x8*)&Qs[(wq * 16 + lc) * PSTR + 32 + lq * 8];

    f32x4 of[4] = {};
    float l_lane[4] = {};
    const float QSC = 0.125f * LOG2E;

    for (int j0 = 0; j0 < S_; j0 += 128) {
        __syncthreads();
        {
            const ushort* ksrc0 = qkv + (size_t)(b * S_ + j0 + r) * 1536 + 512 + h * 64 + cg * 16;
            const ushort* ksrc1 = ksrc0 + (size_t)64 * 1536;
            *(uint4*)&Ks0[r * PSTR + cg * 16]     = ((const uint4*)ksrc0)[0];
            *(uint4*)&Ks0[r * PSTR + cg * 16 + 8] = ((const uint4*)ksrc0)[1];
            *(uint4*)&Ks1[r * PSTR + cg * 16]     = ((const uint4*)ksrc1)[0];
            *(uint4*)&Ks1[r * PSTR + cg * 16 + 8] = ((const uint4*)ksrc1)[1];
            ushort vv[16];
            *(uint4*)&vv[0] = ((const uint4*)(ksrc0 + 512))[0];
            *(uint4*)&vv[8] = ((const uint4*)(ksrc0 + 512))[1];
            #pragma unroll
            for (int dd = 0; dd < 16; dd++)
                Vts0[vswz(cg * 16 + dd, r)] = vv[dd];
            *(uint4*)&vv[0] = ((const uint4*)(ksrc1 + 512))[0];
            *(uint4*)&vv[8] = ((const uint4*)(ksrc1 + 512))[1];
            #pragma unroll
            for (int dd = 0; dd < 16; dd++)
                Vts1[vswz(cg * 16 + dd, r)] = vv[dd];
        }
        __syncthreads();

        ATTN_SUB(Ks0, Vts0, j0);
        ATTN_SUB(Ks1, Vts1, j0 + 64);
    }

    float inv[4];
    #pragma unroll
    for (int rr = 0; rr < 4; rr++) {
        float s = l_lane[rr];
        s += __shfl_xor(s, 1);
        s += __shfl_xor(s, 2);
        s += __shfl_xor(s, 4);
        s += __shfl_xor(s, 8);
        inv[rr] = 1.f / s;
    }
    #pragma unroll
    for (int ni = 0; ni < 4; ni++)
        #pragma unroll
        for (int rr = 0; rr < 4; rr++) {
            int row = i0 + wq * 16 + lq * 4 + rr;
            ao[(size_t)(b * S_ + row) * D_ + h * 64 + ni * 16 + lc] = f2bf(of[ni][rr] * inv[rr]);
        }
}

// ---------------------------------------------------------------------------
// xb = bf16( LayerNorm(xb + pb + bvec) * g + b )
// ---------------------------------------------------------------------------
__device__ __forceinline__ float block_sum(float v, float* red) {
    #pragma unroll
    for (int off = 32; off > 0; off >>= 1) v += __shfl_down(v, off);
    int t = threadIdx.x;
    if ((t & 63) == 0) red[t >> 6] = v;
    __syncthreads();
    float r = red[0] + red[1] + red[2] + red[3];
    __syncthreads();
    return r;
}

__global__ __launch_bounds__(256) void add_ln_kernel(
    ushort* __restrict__ xb, const ushort* __restrict__ pb,
    const float* __restrict__ bvec,
    const float* __restrict__ g, const float* __restrict__ bta)
{
    __shared__ float red[4];
    const int row = blockIdx.x;
    const int t = threadIdx.x;
    const size_t base = (size_t)row * D_;
    float v0 = bf2f(xb[base + t])       + bf2f(pb[base + t])       + bvec[t];
    float v1 = bf2f(xb[base + t + 256]) + bf2f(pb[base + t + 256]) + bvec[t + 256];
    float mean = block_sum(v0 + v1, red) * (1.f / (float)D_);
    float d0 = v0 - mean, d1 = v1 - mean;
    float var = block_sum(d0 * d0 + d1 * d1, red) * (1.f / (float)D_);
    float inv = rsqrtf(var + 1e-5f);
    float o0 = d0 * inv * g[t] + bta[t];
    float o1 = d1 * inv * g[t + 256] + bta[t + 256];
    xb[base + t]       = f2bf(o0);
    xb[base + t + 256] = f2bf(o1);
}

// ---------------------------------------------------------------------------
// Layer-5 "last position only" path: 16 rows (one per batch).
// ---------------------------------------------------------------------------
// C[b, m] = sum_k A[b-row][k] * W[m][k] + bias[m]  (A row = A + b*aStride + aOff)
__global__ __launch_bounds__(256) void gemm_last(
    const ushort* __restrict__ A, int aStride, int aOff,
    const ushort* __restrict__ W, const float* __restrict__ bias,
    ushort* __restrict__ C, int K, int M, int relu)
{
    __shared__ ushort as_[2048];
    const int b  = blockIdx.y;
    const int m0 = blockIdx.x * 64;
    const int t  = threadIdx.x;
    const ushort* arow = A + (size_t)b * aStride + aOff;
    for (int k = t * 8; k < K; k += 2048)
        *(uint4*)&as_[k] = *(const uint4*)&arow[k];
    __syncthreads();
    const int col = m0 + (t >> 2);
    const int kl  = t & 3;
    const int kq  = K >> 2;
    const ushort* wrow = W + (size_t)col * K + kl * kq;
    const ushort* ar   = &as_[kl * kq];
    float acc = 0.f;
    for (int k = 0; k < kq; k += 8) {
        ushort uw[8], ua[8];
        *(uint4*)uw = *(const uint4*)&wrow[k];
        *(uint4*)ua = *(const uint4*)&ar[k];
        #pragma unroll
        for (int i = 0; i < 8; i++) acc += bf2f(ua[i]) * bf2f(uw[i]);
    }
    acc += __shfl_xor(acc, 1);
    acc += __shfl_xor(acc, 2);
    if (kl == 0) {
        float val = acc + bias[col];
        if (relu) val = fmaxf(val, 0.f);
        C[(size_t)b * M + col] = f2bf(val);
    }
}

// One query (last position) per (h, b). kv row-stride 1024: k @0, v @512.
__global__ __launch_bounds__(256) void attn_last_kernel(
    const ushort* __restrict__ ql, const ushort* __restrict__ kv,
    const ushort* __restrict__ biasb, ushort* __restrict__ ao16)
{
    const int h = blockIdx.x, b = blockIdx.y;
    const int t = threadIdx.x;
    __shared__ float qs[64];
    __shared__ float sc[512];
    __shared__ float red[4];
    __shared__ float po[4][64];
    if (t < 64) qs[t] = bf2f(ql[b * 512 + h * 64 + t]);
    __syncthreads();
    const float QSC = 0.125f * LOG2E;
    const ushort* brow = biasb + ((size_t)(b * S_ + S_ - 1)) * S_;
    float psum = 0.f;
    for (int j = t; j < 512; j += 256) {
        const ushort* krow = kv + ((size_t)(b * S_ + j)) * 1024 + h * 64;
        float acc = 0.f;
        #pragma unroll
        for (int d8 = 0; d8 < 8; d8++) {
            ushort uk[8];
            *(uint4*)uk = ((const uint4*)krow)[d8];
            #pragma unroll
            for (int i = 0; i < 8; i++) acc += qs[d8 * 8 + i] * bf2f(uk[i]);
        }
        float p = __builtin_amdgcn_exp2f(fmaf(acc, QSC, bf2f(brow[j])));
        sc[j] = p;
        psum += p;
    }
    float inv = 1.f / block_sum(psum, red);
    const int d = t & 63, c = t >> 6;
    float acc = 0.f;
    const ushort* vbase = kv + (size_t)(b * S_) * 1024 + 512 + h * 64 + d;
    for (int j = c * 128; j < c * 128 + 128; j++)
        acc += sc[j] * bf2f(vbase[(size_t)j * 1024]);
    po[c][d] = acc;
    __syncthreads();
    if (t < 64) {
        float r = (po[0][t] + po[1][t] + po[2][t] + po[3][t]) * inv;
        ao16[b * 512 + h * 64 + t] = f2bf(r);
    }
}

// LN over the 16 last-position rows: xb_row = LN(xb_row + p16_row)*g + b
__global__ __launch_bounds__(256) void ln_last_kernel(
    ushort* __restrict__ xb, const ushort* __restrict__ p16,
    const float* __restrict__ g, const float* __restrict__ bta)
{
    __shared__ float red[4];
    const int b = blockIdx.x;
    const int t = threadIdx.x;
    const size_t bx = ((size_t)(b * S_ + S_ - 1)) * D_;
    const size_t bp = (size_t)b * D_;
    float v0 = bf2f(xb[bx + t])       + bf2f(p16[bp + t]);
    float v1 = bf2f(xb[bx + t + 256]) + bf2f(p16[bp + t + 256]);
    float mean = block_sum(v0 + v1, red) * (1.f / (float)D_);
    float d0 = v0 - mean, d1 = v1 - mean;
    float var = block_sum(d0 * d0 + d1 * d1, red) * (1.f / (float)D_);
    float inv = rsqrtf(var + 1e-5f);
    xb[bx + t]       = f2bf(d0 * inv * g[t] + bta[t]);
    xb[bx + t + 256] = f2bf(d1 * inv * g[t + 256] + bta[t + 256]);
}

// ---------------------------------------------------------------------------
// logits: grid (B, 8); reads bf16 last-row
// ---------------------------------------------------------------------------
__global__ __launch_bounds__(256) void logits_kernel(
    const ushort* __restrict__ xb, const float* __restrict__ lw, float* __restrict__ out)
{
    __shared__ float xs[D_];
    const int b = blockIdx.x;
    const int vchunk = blockIdx.y;
    const int t = threadIdx.x;
    const ushort* xrow = xb + ((size_t)(b * S_ + (S_ - 1)) * D_);
    xs[t] = bf2f(xrow[t]);
    xs[t + 256] = bf2f(xrow[t + 256]);
    __syncthreads();
    for (int vv = vchunk * 128 + t; vv < vchunk * 128 + 128; vv += 256) {
        const float* wr = lw + (size_t)vv * D_;
        float acc = 0.f;
        #pragma unroll 8
        for (int d = 0; d < D_; d += 4) {
            float4 w4 = *(const float4*)&wr[d];
            acc += xs[d] * w4.x + xs[d + 1] * w4.y + xs[d + 2] * w4.z + xs[d + 3] * w4.w;
        }
        out[(size_t)b * VOCAB_ + vv] = acc;
    }
}

// ---------------------------------------------------------------------------
extern "C" void kernel_launch(void* const* d_in, const int* in_sizes, int n_in,
                              void* d_out, int out_size, void* d_ws, size_t ws_size,
                              hipStream_t stream)
{
    const int* raw_x = (const int*)d_in[0];
    const int* sdeg  = (const int*)d_in[1];
    const int* pci   = (const int*)d_in[2];
    const int* pcn   = (const int*)d_in[3];
    const int* sbi   = (const int*)d_in[4];
    const int* sbn   = (const int*)d_in[5];
    const float* vemb = (const float*)d_in[6];
    const float* demb = (const float*)d_in[7];
    const float* arel = (const float*)d_in[8];
    const float* renc = (const float*)d_in[9];
    const float* Wq = (const float*)d_in[10];
    const float* bq = (const float*)d_in[11];
    const float* Wk = (const float*)d_in[12];
    const float* bk = (const float*)d_in[13];
    const float* Wv = (const float*)d_in[14];
    const float* bv = (const float*)d_in[15];
    const float* Wo = (const float*)d_in[16];
    const float* bo = (const float*)d_in[17];
    const float* W1 = (const float*)d_in[18];
    const float* b1 = (const float*)d_in[19];
    const float* W2 = (const float*)d_in[20];
    const float* b2 = (const float*)d_in[21];
    const float* lng = (const float*)d_in[22];
    const float* lnb = (const float*)d_in[23];
    const float* lw  = (const float*)d_in[24];
    float* out = (float*)d_out;

    float* wsf = (float*)d_ws;
    const size_t X = (size_t)BS_ * D_;               // 4,194,304 floats
    ushort* xb   = (ushort*)wsf;                      // [0, 0.5X)
    ushort* qkvb = (ushort*)(wsf + X / 2);            // [0.5X, 2X)   bf16 BS*1536 (also layer-5 KV BS*1024)
    ushort* ao   = (ushort*)(wsf + 2 * X);            // [2X, 2.5X)   bf16 BS*512
    ushort* h1   = (ushort*)(wsf + (X * 5) / 2);      // [2.5X, 4.5X) bf16 BS*2048
    ushort* projb= (ushort*)(wsf + (X * 9) / 2);      // [4.5X, 5X)   bf16 BS*512
    float*  bias = wsf + 5 * X;                       // [5X, 6X)     fp32 scatter
    ushort* biasb= (ushort*)(wsf + 6 * X);            // [6X, 6.5X)   bf16 scaled
    ushort* wb   = (ushort*)(wsf + (X * 13) / 2);     // weights bf16: 18,874,368 shorts
    ushort* wqkv_b = wb;                              // L*1536*512
    ushort* wo_b   = wb + 4718592;                    // L*512*512
    ushort* w1_b   = wb + 6291456;                    // L*2048*512
    ushort* w2_b   = wb + 12582912;                   // L*512*2048
    float*  bqkv   = wsf + (X * 13) / 2 + 9437184;    // L*1536 floats
    // layer-5 small buffers (after bqkv, 16 KB pad)
    ushort* ql16 = (ushort*)(bqkv + 16384);           // 16*512
    ushort* ao16 = ql16 + 16 * 512;                   // 16*512
    ushort* p16  = ao16 + 16 * 512;                   // 16*512
    ushort* h1l  = p16  + 16 * 512;                   // 16*2048

    // --- embeddings (direct to bf16) ---
    embed_kernel<<<(B_ * S_ * D_) / 256, 256, 0, stream>>>(raw_x, sdeg, vemb, demb, xb);
    relnow_kernel<<<B_, D_, 0, stream>>>(pcn, sbn, arel, xb);

    // --- attention bias matrix (fp32 scatter -> bf16 log2e-scaled) ---
    hipMemsetAsync(bias, 0, (size_t)B_ * S_ * S_ * sizeof(float), stream);
    bias_scatter_kernel<<<(NPC_ + NS_ + 255) / 256, 256, 0, stream>>>(pci, sbi, renc, bias);
    bias_cast_kernel<<<(B_ * S_ * S_ / 4) / 256, 256, 0, stream>>>(bias, biasb);

    // --- weight prep ---
    pack_qkv_kernel<<<(L_ * 1536 * 512) / 256, 256, 0, stream>>>(Wq, Wk, Wv, wqkv_b);
    pack_bqkv_kernel<<<(L_ * 1536 + 255) / 256, 256, 0, stream>>>(bq, bk, bv, bqkv);
    cast4_kernel<<<(L_ * 512 * 512) / 4 / 256, 256, 0, stream>>>(Wo, wo_b, L_ * 512 * 512 / 4);
    cast4_kernel<<<(L_ * 2048 * 512) / 4 / 256, 256, 0, stream>>>(W1, w1_b, L_ * 2048 * 512 / 4);
    cast4_kernel<<<(L_ * 512 * 2048) / 4 / 256, 256, 0, stream>>>(W2, w2_b, L_ * 512 * 2048 / 4);

    dim3 blk(256);
    // ---- layers 0..4: full path ----
    for (int l = 0; l < L_ - 1; l++) {
        gemm_bf16<<<dim3(BS_ / 128, 1536 / 128), blk, 0, stream>>>(
            xb, wqkv_b + (size_t)l * 1536 * 512, bqkv + l * 1536, qkvb, 512, 1536, 2);

        attn_kernel<<<dim3(S_ / 64, H_, B_), blk, 0, stream>>>(qkvb, biasb, ao);

        gemm64<<<dim3(BS_ / 128, 512 / 64), blk, 0, stream>>>(
            ao, wo_b + (size_t)l * 512 * 512, projb, 512, 512);
        add_ln_kernel<<<BS_, blk, 0, stream>>>(xb, projb, bo + l * 512,
                                               lng + l * D_, lnb + l * D_);

        gemm_bf16<<<dim3(BS_ / 128, 2048 / 128), blk, 0, stream>>>(
            xb, w1_b + (size_t)l * 2048 * 512, b1 + l * 2048, h1, 512, 2048, 1);
        gemm64<<<dim3(BS_ / 128, 512 / 64), blk, 0, stream>>>(
            h1, w2_b + (size_t)l * 512 * 2048, projb, 2048, 512);
        add_ln_kernel<<<BS_, blk, 0, stream>>>(xb, projb, b2 + l * 512,
                                               lng + l * D_, lnb + l * D_);
    }

    // ---- layer 5: only the last position survives to the output ----
    {
        const int l = L_ - 1;
        // K,V for ALL positions (queries need every key/value)
        gemm_bf16<<<dim3(BS_ / 128, 1024 / 128), blk, 0, stream>>>(
            xb, wqkv_b + (size_t)l * 1536 * 512 + (size_t)512 * 512,
            bqkv + l * 1536 + 512, qkvb, 512, 1024, 2);
        // Q only for the 16 last rows
        gemm_last<<<dim3(512 / 64, B_), blk, 0, stream>>>(
            xb, S_ * D_, (S_ - 1) * D_,
            wqkv_b + (size_t)l * 1536 * 512, bqkv + l * 1536, ql16, 512, 512, 0);
        attn_last_kernel<<<dim3(H_, B_), blk, 0, stream>>>(ql16, qkvb, biasb, ao16);
        // O-proj (16 rows), bias bo folded here
        gemm_last<<<dim3(512 / 64, B_), blk, 0, stream>>>(
            ao16, 512, 0, wo_b + (size_t)l * 512 * 512, bo + l * 512, p16, 512, 512, 0);
        ln_last_kernel<<<B_, blk, 0, stream>>>(xb, p16, lng + l * D_, lnb + l * D_);
        // FFN (16 rows)
        gemm_last<<<dim3(2048 / 64, B_), blk, 0, stream>>>(
            xb, S_ * D_, (S_ - 1) * D_,
            w1_b + (size_t)l * 2048 * 512, b1 + l * 2048, h1l, 512, 2048, 1);
        gemm_last<<<dim3(512 / 64, B_), blk, 0, stream>>>(
            h1l, 2048, 0, w2_b + (size_t)l * 512 * 2048, b2 + l * 512, p16, 2048, 512, 0);
        ln_last_kernel<<<B_, blk, 0, stream>>>(xb, p16, lng + l * D_, lnb + l * D_);
    }

    logits_kernel<<<dim3(B_, 8), blk, 0, stream>>>(xb, lw, out);
}